// Round 4
// baseline (257.487 us; speedup 1.0000x reference)
//
#include <hip/hip_runtime.h>
#include <math.h>

// ---------------- problem constants ----------------
#define T_LEN   32768
#define NK      192
#define NB      2
#define KDIR    48            // k < KDIR (j<=2): exact direct conv path
#define MAXM    56            // max half-support for direct path (true max 48)

struct SParams {
  int m1e[144];   // even half-support of stage-1 kernel per k-48
  int slot[144];  // padded complex tap count per k-48 (mult of 512)
  int voff[64];   // v-table word offset, SMALL path only (j<=6)
  int ab[9];      // A-arena word base per octave j-3
  int jb[11];     // block-range bases: j=11..3 (9), direct, end
};

__device__ __forceinline__ int j2_of_q(int q) {
  // ceil(3.25 * 2^(q/16)) : {4,...,4,5,...,5,6,...,6,7}
  return 4 + (q >= 5) + (q >= 10) + (q >= 15);
}

// ---- k_pre: small-path v-tables (ki<64, slots<=1536) + zero atomic arenas ----
__global__ __launch_bounds__(256) void k_pre(float* __restrict__ ws, SParams P,
                                             int zbase, int zn) {
  int tid = threadIdx.x;
  if (blockIdx.y == 64) {
    for (int i = blockIdx.x * 256 + tid; i < zn; i += 512) ws[zbase + i] = 0.f;
    return;
  }
  int ki = blockIdx.y;                 // 0..63 (j=3..6)
  int slotc = P.slot[ki];
  int M1e = P.m1e[ki];
  float* dst = ws + P.voff[ki];
  int nent = 2 * M1e + 2;              // m in [-M1e, M1e+1]
  int k = ki + 48;
  int j = k >> 4, q = k & 15;
  float sig = 2.f * exp2f((float)(16 * j + q) * 0.0625f);
  float s1 = sig * 0.86602540378f;
  float gc = -0.5f / (s1 * s1);
  float om = 6.28318530718f / sig;
  float norm = 1.f / (2.50662827463f * s1 * erff((float)M1e / (1.41421356237f * s1)));
  #pragma unroll
  for (int e0 = 0; e0 < 4; ++e0) {
    int e = blockIdx.x * 1024 + e0 * 256 + tid;
    if (e >= slotc) continue;
    if (e >= nent) { dst[2 * e] = 0.f; dst[2 * e + 1] = 0.f; continue; }
    float mm = (float)(e - M1e);
    float g = __expf(gc * mm * mm) * norm;
    float sn, cs; __sincosf(om * mm, &sn, &cs);
    dst[2 * e] = g * cs;
    dst[2 * e + 1] = g * sn;
  }
}

// ================= stage 1 =================
// deep path (j=7..11): block = (j, q, output-tile, tap-chunk). x window staged
// in LDS; v computed ON THE FLY (same fp32 formulas as k_pre) — no v stream.
// small path (j=3..6): thread-per-(output,batch,tap-segment); v broadcast reads.
// direct path (j<=2): exact conv, merged as trailing block range.

template<int J, int G, int S, int CH>
__device__ __forceinline__ void deep_path(const float* __restrict__ x,
                                          float* __restrict__ ws, const SParams& P,
                                          int q, int rc, int tid,
                                          float* xs, float* red) {
  constexpr int d = 1 << J;
  constexpr int E = 2048;                    // taps per staged window
  constexpr int W = E + (G - 1) * d + 2;     // staged samples (even) <= 4098
  const int tile = rc / CH;
  const int chunk = rc % CH;
  const int ki = 16 * (J - 3) + q;
  const int J2 = j2_of_q(q);
  const int M1e = P.m1e[ki];
  const int slot = P.slot[ki];
  const int e_base = chunk * (S * E);
  if (e_base >= slot) return;                // empty chunk for this q
  const int nent = 2 * M1e + 2;
  const int n0 = tile * G;
  const int ubase0 = (n0 - J2) * d - M1e;    // u at e=0, g=0 (even)
  const float* xb0 = x;
  const float* xb1 = x + T_LEN;
  // on-the-fly v constants (identical fp32 math to k_pre)
  float sig = 2.f * exp2f((float)(16 * J + q) * 0.0625f);
  float s1 = sig * 0.86602540378f;
  float gc = -0.5f / (s1 * s1);
  float om = 6.28318530718f / sig;
  float norm = 1.f / (2.50662827463f * s1 * erff((float)M1e / (1.41421356237f * s1)));

  float acc[4 * G];
  #pragma unroll
  for (int i = 0; i < 4 * G; ++i) acc[i] = 0.f;

  #pragma unroll
  for (int s = 0; s < S; ++s) {
    int e0 = e_base + s * E;
    if (e0 >= slot) break;                   // uniform across block
    int ub = ubase0 + e0;
    int Ech = slot - e0; if (Ech > E) Ech = E;   // multiple of 512
    int Wn = Ech + (G - 1) * d + 2;
    if (ub >= T_LEN || ub + Wn <= 0) continue;   // window fully OOB (uniform)
    int Wh = (Wn + 1) >> 1;
    // stage: xs float4 i = samples (2i, 2i+1) as (xa0, xb0, xa1, xb1)
    for (int i = tid; i < Wh; i += 256) {
      int u0 = ub + 2 * i;                      // even
      bool ok = (unsigned)u0 <= (unsigned)(T_LEN - 2);
      int uc = ok ? u0 : 0;
      float2 a = *(const float2*)(xb0 + uc);
      float2 b = *(const float2*)(xb1 + uc);
      float4 w;
      w.x = ok ? a.x : 0.f; w.y = ok ? b.x : 0.f;
      w.z = ok ? a.y : 0.f; w.w = ok ? b.y : 0.f;
      *(float4*)(xs + 4 * i) = w;
    }
    __syncthreads();
    int pend = Ech >> 9;                        // 512 taps per pass
    const float4* xp0 = (const float4*)xs + tid;
    int et = e0 + 2 * tid;                      // this thread's tap at ps=0
    for (int ps = 0; ps < pend; ++ps) {
      int e = et + (ps << 9);
      float vx, vy, vz, vw;
      if (e < nent) {
        float mm0 = (float)(e - M1e), mm1 = mm0 + 1.f;
        float g0 = __expf(gc * mm0 * mm0) * norm;
        float g1 = __expf(gc * mm1 * mm1) * norm;
        float sn0, cs0, sn1, cs1;
        __sincosf(om * mm0, &sn0, &cs0);
        __sincosf(om * mm1, &sn1, &cs1);
        vx = g0 * cs0; vy = g0 * sn0; vz = g1 * cs1; vw = g1 * sn1;
      } else { vx = 0.f; vy = 0.f; vz = 0.f; vw = 0.f; }
      const float4* xp = xp0 + (ps << 8);
      #pragma unroll
      for (int g = 0; g < G; ++g) {
        float4 xv = xp[g * (d >> 1)];
        acc[4 * g + 0] += vx * xv.x + vz * xv.z;   // ar0
        acc[4 * g + 1] += vy * xv.x + vw * xv.z;   // ai0
        acc[4 * g + 2] += vx * xv.y + vz * xv.w;   // ar1
        acc[4 * g + 3] += vy * xv.y + vw * xv.w;   // ai1
      }
    }
    __syncthreads();
  }

  // block-wide reduction of 4G values
  #pragma unroll
  for (int st = 1; st < 64; st <<= 1) {
    #pragma unroll
    for (int i = 0; i < 4 * G; ++i) acc[i] += __shfl_xor(acc[i], st, 64);
  }
  int wv = tid >> 6;
  if ((tid & 63) == 0) {
    #pragma unroll
    for (int gg = 0; gg < G; ++gg)
      *(float4*)(red + wv * 64 + 4 * gg) =
        make_float4(acc[4 * gg], acc[4 * gg + 1], acc[4 * gg + 2], acc[4 * gg + 3]);
  }
  __syncthreads();
  if (tid < 4 * G)
    red[256 + tid] = red[tid] + red[64 + tid] + red[128 + tid] + red[192 + tid];
  __syncthreads();
  if (tid < G) {
    int nidx = n0 + tid;
    int Ncu = (32767 >> J) + 17;
    if (nidx < Ncu) {
      float ar0 = red[256 + 4 * tid], ai0 = red[256 + 4 * tid + 1];
      float ar1 = red[256 + 4 * tid + 2], ai1 = red[256 + 4 * tid + 3];
      float ndf = (float)((nidx - J2) * d);
      float rev = ndf * exp2f(-(float)(16 * (J + 1) + q) * 0.0625f);
      rev -= floorf(rev);
      float sn, cs; __sincosf(rev * 6.28318530718f, &sn, &cs);
      float* ap = ws + P.ab[J - 3] + (q * 2) * Ncu * 2;
      float r0 = ar0 * cs - ai0 * sn, i0 = ar0 * sn + ai0 * cs;
      float r1 = ar1 * cs - ai1 * sn, i1 = ar1 * sn + ai1 * cs;
      if (CH == 1) {
        *(float2*)(ap + 2 * nidx) = make_float2(r0, i0);
        *(float2*)(ap + 2 * (Ncu + nidx)) = make_float2(r1, i1);
      } else {
        atomicAdd(ap + 2 * nidx, r0);
        atomicAdd(ap + 2 * nidx + 1, i0);
        atomicAdd(ap + 2 * (Ncu + nidx), r1);
        atomicAdd(ap + 2 * (Ncu + nidx) + 1, i1);
      }
    }
  }
}

template<int J, int TOUT, int LT>
__device__ __forceinline__ void small_path(const float* __restrict__ x,
                                           float* __restrict__ ws, const SParams& P,
                                           int q, int tile, int tid,
                                           float* xs, float* red) {
  constexpr int d = 1 << J;
  constexpr int TASKS = TOUT * 2;
  constexpr int SPLIT = 256 / TASKS;
  const int ki = 16 * (J - 3) + q;
  const int J2 = j2_of_q(q);
  const int M1e = P.m1e[ki];
  const int nent = 2 * M1e + 2;               // even
  const float* vt = ws + P.voff[ki];
  const int Ncu = (32767 >> J) + 17;
  const int o0 = tile * TOUT;
  const int ub = (o0 - J2) * d - M1e;
  const int W = (TOUT - 1) * d + nent;
  const int PS = W + (((W - 1) >> J) << 1) + 4;   // plane stride (floats)
  const float* xb0 = x;
  const float* xb1 = x + T_LEN;
  // stage both planes; addr(s) = s + 2*(s>>J) (pad 2 floats per d; even-s b64
  // reads never straddle a pad since s stays even and d is even)
  for (int i = tid; i < W; i += 256) {
    int u = ub + i;
    bool ok = (unsigned)u < (unsigned)T_LEN;
    int uc = ok ? u : 0;
    float a = xb0[uc]; a = ok ? a : 0.f;
    float bv = xb1[uc]; bv = ok ? bv : 0.f;
    int ad = i + ((i >> J) << 1);
    xs[ad] = a; xs[PS + ad] = bv;
  }
  __syncthreads();
  int o = tid & (TOUT - 1);
  int b = (tid >> LT) & 1;
  int seg = tid >> (LT + 1);                   // [0, SPLIT)
  int per = ((nent >> 1) + SPLIT - 1) / SPLIT; // tap-pairs per segment
  int e_lo = 2 * per * seg; if (e_lo > nent) e_lo = nent;
  int e_hi = e_lo + 2 * per; if (e_hi > nent) e_hi = nent;
  const float* pl = xs + b * PS;
  int sb = o * d;                              // even
  float ar = 0.f, ai = 0.f;
  #pragma unroll 4
  for (int e = e_lo; e < e_hi; e += 2) {
    float4 v = *(const float4*)(vt + 2 * e);   // block-uniform broadcast
    int s = sb + e;
    float2 xv = *(const float2*)(pl + s + ((s >> J) << 1));
    ar += v.x * xv.x + v.z * xv.y;
    ai += v.y * xv.x + v.w * xv.y;
  }
  if (SPLIT > 1) {
    red[tid] = ar; red[256 + tid] = ai;
    __syncthreads();
    if (seg == 0) {
      #pragma unroll
      for (int ss = 1; ss < SPLIT; ++ss) {
        ar += red[tid + ss * TASKS];
        ai += red[256 + tid + ss * TASKS];
      }
    }
  }
  if (seg == 0 && o0 + o < Ncu) {
    int nidx = o0 + o;
    float ndf = (float)((nidx - J2) * d);
    float rev = ndf * exp2f(-(float)(16 * (J + 1) + q) * 0.0625f);
    rev -= floorf(rev);
    float sn, cs; __sincosf(rev * 6.28318530718f, &sn, &cs);
    float* ap = ws + P.ab[J - 3] + (q * 2) * Ncu * 2;
    *(float2*)(ap + 2 * (b * Ncu + nidx)) = make_float2(ar * cs - ai * sn, ar * sn + ai * cs);
  }
}

// direct exact conv for j<=2: thread -> 4 consecutive outputs; sliding 8-float
// register window; x via ds_read_b128; coalesced float4 store.
__device__ __forceinline__ void direct_path(const float* __restrict__ x,
                                            const float* __restrict__ fr,
                                            const float* __restrict__ fi,
                                            float* __restrict__ out, int Lmax,
                                            int rem, int tid,
                                            float* xs, float* red) {
  int b = rem / 1536;
  int r2 = rem - b * 1536;
  int k = r2 >> 5;
  int t0 = (r2 & 31) << 10;
  int j = k >> 4, q = k & 15;
  int M = (int)ceil(6.0 * exp2((double)j + (double)q * 0.0625)) + 2; // >= true M
  int P = Lmax >> 1;
  float* frs = red;            // 116 floats
  float* fis = red + 128;      // 116 floats
  int xlen = 1024 + 2 * M;
  const float* xb = x + b * T_LEN;
  for (int i = tid; i < xlen; i += 256) {
    int u = t0 - M + i;
    xs[i] = (u >= 0 && u < T_LEN) ? xb[u] : 0.f;
  }
  if (tid < 4) xs[xlen + tid] = 0.f;          // zero pad (overrun reads)
  const float* frk = fr + (size_t)k * Lmax + (P - M);
  const float* fik = fi + (size_t)k * Lmax + (P - M);
  int tl = 2 * M + 1;
  for (int i = tid; i < tl; i += 256) { frs[i] = frk[i]; fis[i] = fik[i]; }
  if (tid < 3) { frs[tl + tid] = 0.f; fis[tl + tid] = 0.f; }   // zero pad
  __syncthreads();
  float ar0 = 0.f, ar1 = 0.f, ar2 = 0.f, ar3 = 0.f;
  float ai0 = 0.f, ai1 = 0.f, ai2 = 0.f, ai3 = 0.f;
  const float4* xsv = (const float4*)(xs + 4 * tid);
  float4 w0 = xsv[0];
  int groups = (tl + 3) >> 2;
  for (int g = 0; g < groups; ++g) {
    float4 w1 = xsv[g + 1];
    float4 f4 = *(const float4*)(frs + 4 * g);
    float4 h4 = *(const float4*)(fis + 4 * g);
    ar0 += f4.x * w0.x + f4.y * w0.y + f4.z * w0.z + f4.w * w0.w;
    ai0 += h4.x * w0.x + h4.y * w0.y + h4.z * w0.z + h4.w * w0.w;
    ar1 += f4.x * w0.y + f4.y * w0.z + f4.z * w0.w + f4.w * w1.x;
    ai1 += h4.x * w0.y + h4.y * w0.z + h4.z * w0.w + h4.w * w1.x;
    ar2 += f4.x * w0.z + f4.y * w0.w + f4.z * w1.x + f4.w * w1.y;
    ai2 += h4.x * w0.z + h4.y * w0.w + h4.z * w1.x + h4.w * w1.y;
    ar3 += f4.x * w0.w + f4.y * w1.x + f4.z * w1.y + f4.w * w1.z;
    ai3 += h4.x * w0.w + h4.y * w1.x + h4.z * w1.y + h4.w * w1.z;
    w0 = w1;
  }
  size_t ob = (size_t)(b * NK + k) * T_LEN + t0 + 4 * tid;
  float4 res;
  res.x = sqrtf(ar0 * ar0 + ai0 * ai0);
  res.y = sqrtf(ar1 * ar1 + ai1 * ai1);
  res.z = sqrtf(ar2 * ar2 + ai2 * ai2);
  res.w = sqrtf(ar3 * ar3 + ai3 * ai3);
  *(float4*)(out + ob) = res;
}

__global__ __launch_bounds__(256) void k_s1(const float* __restrict__ x,
                                            const float* __restrict__ fr,
                                            const float* __restrict__ fi,
                                            float* __restrict__ out, int Lmax,
                                            float* __restrict__ ws, SParams P) {
  __shared__ __align__(16) float xs[8196];    // 32784 B
  __shared__ __align__(16) float red[512];    // 2048 B
  int bx = blockIdx.x, tid = threadIdx.x;
  int o = 0;
  #pragma unroll
  for (int t = 1; t < 10; ++t) if (bx >= P.jb[t]) o = t;
  int rem = bx - P.jb[o];
  if (o == 9) { direct_path(x, fr, fi, out, Lmax, rem, tid, xs, red); return; }
  int j = 11 - o;
  int rc = rem >> 4, q = rem & 15;
  switch (j) {
    case 11: deep_path<11, 2, 2, 12>(x, ws, P, q, rc, tid, xs, red); break;
    case 10: deep_path<10, 3, 2, 6>(x, ws, P, q, rc, tid, xs, red); break;
    case 9:  deep_path<9, 4, 2, 3>(x, ws, P, q, rc, tid, xs, red); break;
    case 8:  deep_path<8, 8, 3, 1>(x, ws, P, q, rc, tid, xs, red); break;
    case 7:  deep_path<7, 16, 2, 1>(x, ws, P, q, rc, tid, xs, red); break;
    case 6:  small_path<6, 32, 5>(x, ws, P, q, rc, tid, xs, red); break;
    case 5:  small_path<5, 64, 6>(x, ws, P, q, rc, tid, xs, red); break;
    case 4:  small_path<4, 128, 7>(x, ws, P, q, rc, tid, xs, red); break;
    default: small_path<3, 128, 7>(x, ws, P, q, rc, tid, xs, red); break;
  }
}

// ---------------- stage 2: 8 outputs/thread (4 t-pos x 2 batches) ----------------
__global__ __launch_bounds__(256) void k_stage2(const float* __restrict__ ws,
                                                float* __restrict__ out, SParams P) {
  int k = KDIR + blockIdx.y;
  int j = k >> 4, q = k & 15;
  int d = 1 << j;
  int J2 = j2_of_q(q);
  float sig = 2.f * exp2f((float)(16 * j + q) * 0.0625f);
  float s2 = sig * 0.5f;
  int Ncu = (32767 >> j) + 17;
  const float* A0 = ws + P.ab[j - 3] + (q * 2) * Ncu * 2;
  const float* A1 = A0 + Ncu * 2;
  int t0 = blockIdx.x * 256 + threadIdx.x;   // [0, 8192); outputs t0 + 8192*i
  int phi = t0 & (d - 1);
  int nb0 = t0 >> j;
  int step = 8192 >> j;                      // same phi at t0 + 8192*i
  int ntap = 2 * J2 + 1;
  float fd = (float)d;
  float inv2 = 1.f / (s2 * s2);
  float u0 = (float)(phi + J2 * d);
  float eg = __expf(-0.5f * u0 * u0 * inv2);
  float mf = __expf((fd * u0 - 0.5f * fd * fd) * inv2);
  float qf = __expf(-fd * fd * inv2);
  float Z = 0.f;
  float sr0 = 0.f, si0 = 0.f, sr1 = 0.f, si1 = 0.f;
  float sr2 = 0.f, si2 = 0.f, sr3 = 0.f, si3 = 0.f;
  float tr0 = 0.f, ti0 = 0.f, tr1 = 0.f, ti1 = 0.f;
  float tr2 = 0.f, ti2 = 0.f, tr3 = 0.f, ti3 = 0.f;
  const float* Ap0 = A0 + 2 * nb0;
  const float* Ap1 = A1 + 2 * nb0;
  for (int rr = 0; rr < ntap; ++rr) {
    float w = eg; eg *= mf; mf *= qf; Z += w;
    float2 a0 = *(const float2*)(Ap0 + 2 * rr);
    float2 a1 = *(const float2*)(Ap0 + 2 * (rr + step));
    float2 a2 = *(const float2*)(Ap0 + 2 * (rr + 2 * step));
    float2 a3 = *(const float2*)(Ap0 + 2 * (rr + 3 * step));
    float2 b0 = *(const float2*)(Ap1 + 2 * rr);
    float2 b1 = *(const float2*)(Ap1 + 2 * (rr + step));
    float2 b2 = *(const float2*)(Ap1 + 2 * (rr + 2 * step));
    float2 b3 = *(const float2*)(Ap1 + 2 * (rr + 3 * step));
    sr0 += w * a0.x; si0 += w * a0.y; sr1 += w * a1.x; si1 += w * a1.y;
    sr2 += w * a2.x; si2 += w * a2.y; sr3 += w * a3.x; si3 += w * a3.y;
    tr0 += w * b0.x; ti0 += w * b0.y; tr1 += w * b1.x; ti1 += w * b1.y;
    tr2 += w * b2.x; ti2 += w * b2.y; tr3 += w * b3.x; ti3 += w * b3.y;
  }
  float zi = 1.f / Z;
  size_t ob0 = (size_t)k * T_LEN + t0;
  size_t ob1 = (size_t)(NK + k) * T_LEN + t0;
  out[ob0]         = sqrtf(sr0 * sr0 + si0 * si0) * zi;
  out[ob0 + 8192]  = sqrtf(sr1 * sr1 + si1 * si1) * zi;
  out[ob0 + 16384] = sqrtf(sr2 * sr2 + si2 * si2) * zi;
  out[ob0 + 24576] = sqrtf(sr3 * sr3 + si3 * si3) * zi;
  out[ob1]         = sqrtf(tr0 * tr0 + ti0 * ti0) * zi;
  out[ob1 + 8192]  = sqrtf(tr1 * tr1 + ti1 * ti1) * zi;
  out[ob1 + 16384] = sqrtf(tr2 * tr2 + ti2 * ti2) * zi;
  out[ob1 + 24576] = sqrtf(tr3 * tr3 + ti3 * ti3) * zi;
}

// ---------------- launch ----------------
extern "C" void kernel_launch(void* const* d_in, const int* in_sizes, int n_in,
                              void* d_out, int out_size, void* d_ws, size_t ws_size,
                              hipStream_t stream) {
  const float* x  = (const float*)d_in[0];
  const float* fr = (const float*)d_in[1];
  const float* fi = (const float*)d_in[2];
  float* out = (float*)d_out;
  float* ws  = (float*)d_ws;
  int Lmax = in_sizes[1] / NK;   // 47069

  // host-side geometry (pure CPU math, deterministic, graph-capture-safe)
  SParams Pm;
  int cur = 0;
  for (int ki = 0; ki < 144; ++ki) {
    int j = (ki + 48) >> 4, q = ki & 15;
    double sig = 2.0 * exp2(((double)(16 * j + q)) / 16.0);
    double s1 = sig * 0.86602540378443864676;
    int M1 = (int)ceil(3.5 * s1);
    int M1e = (M1 + 1) & ~1;
    int slotc = (2 * M1e + 2 + 511) & ~511;   // 512-granular
    Pm.m1e[ki] = M1e;
    Pm.slot[ki] = slotc;
    if (ki < 64) {                             // v-tables only for j<=6
      Pm.voff[ki] = cur;
      cur += 2 * slotc;
    }
  }
  for (int j = 3; j <= 11; ++j) {
    Pm.ab[j - 3] = cur;
    cur += 32 * ((32767 >> j) + 17) * 2;   // 16q * 2b * Ncu * 2 words
  }
  // block ranges: j = 11 down to 3, then direct
  const int DG[5]  = {2, 3, 4, 8, 16};   // outputs per tile, j=11..7
  const int DCH[5] = {12, 6, 3, 1, 1};   // tap-chunks per tile (S*2048 taps)
  const int STO[4] = {32, 64, 128, 128}; // TOUT, j=6..3
  Pm.jb[0] = 0;
  for (int o = 0; o < 9; ++o) {
    int j = 11 - o;
    int Ncu = (32767 >> j) + 17;
    int cnt;
    if (o < 5) {
      int tiles = (Ncu + DG[o] - 1) / DG[o];
      cnt = tiles * DCH[o] * 16;
    } else {
      int TOUT = STO[o - 5];
      cnt = ((Ncu + TOUT - 1) / TOUT) * 16;
    }
    Pm.jb[o + 1] = Pm.jb[o] + cnt;
  }
  Pm.jb[10] = Pm.jb[9] + (T_LEN / 1024) * KDIR * NB;   // + direct blocks (3072)

  // zero the atomic arenas (j=9,10,11)
  int zbase = Pm.ab[6];
  int zn = (Pm.ab[8] + 32 * ((32767 >> 11) + 17) * 2) - zbase;   // 10240 words

  k_pre<<<dim3(2, 65), dim3(256), 0, stream>>>(ws, Pm, zbase, zn);
  k_s1<<<dim3(Pm.jb[10]), dim3(256), 0, stream>>>(x, fr, fi, out, Lmax, ws, Pm);
  k_stage2<<<dim3(T_LEN / (256 * 4), NK - KDIR), dim3(256), 0, stream>>>(ws, out, Pm);
}

// Round 5
// 233.776 us; speedup vs baseline: 1.1014x; 1.1014x over previous
//
#include <hip/hip_runtime.h>
#include <math.h>

// ---------------- problem constants ----------------
#define T_LEN   32768
#define NK      192
#define NB      2
#define KDIR    48            // k < KDIR (j<=2): exact direct conv path
#define MAXM    56            // max half-support for direct path (true max 48)

struct SParams {
  int m1e[144];   // even half-support of stage-1 kernel per k-48
  int slot[144];  // padded complex tap count per k-48 (mult of 512, zero tail)
  int voff[144];  // v-table word offset per k-48
  int ab[9];      // A-arena word base per octave j-3
  int jb[11];     // block-range bases: j=11..3 (9), direct, end
};

__device__ __forceinline__ int j2_of_q(int q) {
  // ceil(3.25 * 2^(q/16)) : {4,...,4,5,...,5,6,...,6,7}
  return 4 + (q >= 5) + (q >= 10) + (q >= 15);
}

// ---- k_pre: all v-tables (zero-filled tails) + zero atomic arenas ----
__global__ __launch_bounds__(256) void k_pre(float* __restrict__ ws, SParams P,
                                             int zbase, int zn) {
  int tid = threadIdx.x;
  if (blockIdx.y == 144) {
    for (int i = blockIdx.x * 256 + tid; i < zn; i += 12032) ws[zbase + i] = 0.f;
    return;
  }
  int ki = blockIdx.y;                 // 0..143
  int slotc = P.slot[ki];
  int M1e = P.m1e[ki];
  float* dst = ws + P.voff[ki];
  int nent = 2 * M1e + 2;              // m in [-M1e, M1e+1]
  int k = ki + 48;
  int j = k >> 4, q = k & 15;
  float sig = 2.f * exp2f((float)(16 * j + q) * 0.0625f);
  float s1 = sig * 0.86602540378f;
  float gc = -0.5f / (s1 * s1);
  float om = 6.28318530718f / sig;
  float norm = 1.f / (2.50662827463f * s1 * erff((float)M1e / (1.41421356237f * s1)));
  #pragma unroll
  for (int e0 = 0; e0 < 4; ++e0) {
    int e = blockIdx.x * 1024 + e0 * 256 + tid;
    if (e >= slotc) continue;
    if (e >= nent) { dst[2 * e] = 0.f; dst[2 * e + 1] = 0.f; continue; }
    float mm = (float)(e - M1e);
    float g = __expf(gc * mm * mm) * norm;
    float sn, cs; __sincosf(om * mm, &sn, &cs);
    dst[2 * e] = g * cs;
    dst[2 * e + 1] = g * sn;
  }
}

// ================= stage 1 =================
// deep path (j=7..11): block = (j, q, output-tile, tap-chunk). x window AND
// v-chunk staged into LDS in the same barrier; inner loop is pure LDS+FMA.
// small path (j=3..6): thread-per-(output,batch,tap-segment); v broadcast reads.
// direct path (j<=2): exact conv, merged as trailing block range.

template<int J, int G, int S, int CH>
__device__ __forceinline__ void deep_path(const float* __restrict__ x,
                                          float* __restrict__ ws, const SParams& P,
                                          int q, int rc, int tid,
                                          float* xs, float* red) {
  constexpr int d = 1 << J;
  constexpr int E = 2048;                    // taps per staged window
  const int tile = rc / CH;
  const int chunk = rc % CH;
  const int ki = 16 * (J - 3) + q;
  const int J2 = j2_of_q(q);
  const int slot = P.slot[ki];
  const int e_base = chunk * (S * E);
  if (e_base >= slot) return;                // empty chunk for this q
  const int M1e = P.m1e[ki];
  const float* vt = ws + P.voff[ki];
  const int n0 = tile * G;
  const int ubase0 = (n0 - J2) * d - M1e;    // u at e=0, g=0 (even)
  const float* xb0 = x;
  const float* xb1 = x + T_LEN;
  float* vs = xs + 8196;                     // v staging region (4096 floats)

  float acc[4 * G];
  #pragma unroll
  for (int i = 0; i < 4 * G; ++i) acc[i] = 0.f;

  #pragma unroll
  for (int s = 0; s < S; ++s) {
    int e0 = e_base + s * E;
    if (e0 >= slot) break;                   // uniform across block
    int Ech = slot - e0; if (Ech > E) Ech = E;   // multiple of 512
    int ub = ubase0 + e0;
    int Wn = Ech + (G - 1) * d + 2;
    if (ub < T_LEN && ub + Wn > 0) {         // window intersects signal (uniform)
      int Wh = (Wn + 1) >> 1;
      // stage x: xs float4 i = samples (2i, 2i+1) as (xa0, xb0, xa1, xb1)
      for (int i = tid; i < Wh; i += 256) {
        int u0 = ub + 2 * i;                    // even
        bool ok = (unsigned)u0 <= (unsigned)(T_LEN - 2);
        int uc = ok ? u0 : 0;
        float2 a = *(const float2*)(xb0 + uc);
        float2 b = *(const float2*)(xb1 + uc);
        float4 w;
        w.x = ok ? a.x : 0.f; w.y = ok ? b.x : 0.f;
        w.z = ok ? a.y : 0.f; w.w = ok ? b.y : 0.f;
        *(float4*)(xs + 4 * i) = w;
      }
      // stage v (zero tail already in table)
      {
        const float4* vg = (const float4*)(vt + 2 * e0);
        float4* vl = (float4*)vs;
        for (int i = tid; i < (Ech >> 1); i += 256) vl[i] = vg[i];
      }
      __syncthreads();
      int pend = Ech >> 9;                      // 512 taps per pass
      const float4* xp0 = (const float4*)xs + tid;
      for (int ps = 0; ps < pend; ++ps) {
        float4 v = *(const float4*)(vs + 4 * tid + (ps << 10));
        const float4* xp = xp0 + (ps << 8);
        #pragma unroll
        for (int g = 0; g < G; ++g) {
          float4 xv = xp[g * (d >> 1)];
          acc[4 * g + 0] += v.x * xv.x + v.z * xv.z;   // ar0
          acc[4 * g + 1] += v.y * xv.x + v.w * xv.z;   // ai0
          acc[4 * g + 2] += v.x * xv.y + v.z * xv.w;   // ar1
          acc[4 * g + 3] += v.y * xv.y + v.w * xv.w;   // ai1
        }
      }
      __syncthreads();
    }
  }

  // block-wide reduction of 4G values
  #pragma unroll
  for (int st = 1; st < 64; st <<= 1) {
    #pragma unroll
    for (int i = 0; i < 4 * G; ++i) acc[i] += __shfl_xor(acc[i], st, 64);
  }
  int wv = tid >> 6;
  if ((tid & 63) == 0) {
    #pragma unroll
    for (int gg = 0; gg < G; ++gg)
      *(float4*)(red + wv * 64 + 4 * gg) =
        make_float4(acc[4 * gg], acc[4 * gg + 1], acc[4 * gg + 2], acc[4 * gg + 3]);
  }
  __syncthreads();
  if (tid < 4 * G)
    red[256 + tid] = red[tid] + red[64 + tid] + red[128 + tid] + red[192 + tid];
  __syncthreads();
  if (tid < G) {
    int nidx = n0 + tid;
    int Ncu = (32767 >> J) + 17;
    if (nidx < Ncu) {
      float ar0 = red[256 + 4 * tid], ai0 = red[256 + 4 * tid + 1];
      float ar1 = red[256 + 4 * tid + 2], ai1 = red[256 + 4 * tid + 3];
      float ndf = (float)((nidx - J2) * d);
      float rev = ndf * exp2f(-(float)(16 * (J + 1) + q) * 0.0625f);
      rev -= floorf(rev);
      float sn, cs; __sincosf(rev * 6.28318530718f, &sn, &cs);
      float* ap = ws + P.ab[J - 3] + (q * 2) * Ncu * 2;
      float r0 = ar0 * cs - ai0 * sn, i0 = ar0 * sn + ai0 * cs;
      float r1 = ar1 * cs - ai1 * sn, i1 = ar1 * sn + ai1 * cs;
      if (CH == 1) {
        *(float2*)(ap + 2 * nidx) = make_float2(r0, i0);
        *(float2*)(ap + 2 * (Ncu + nidx)) = make_float2(r1, i1);
      } else {
        atomicAdd(ap + 2 * nidx, r0);
        atomicAdd(ap + 2 * nidx + 1, i0);
        atomicAdd(ap + 2 * (Ncu + nidx), r1);
        atomicAdd(ap + 2 * (Ncu + nidx) + 1, i1);
      }
    }
  }
}

template<int J, int TOUT, int LT>
__device__ __forceinline__ void small_path(const float* __restrict__ x,
                                           float* __restrict__ ws, const SParams& P,
                                           int q, int tile, int tid,
                                           float* xs, float* red) {
  constexpr int d = 1 << J;
  constexpr int TASKS = TOUT * 2;
  constexpr int SPLIT = 256 / TASKS;
  const int ki = 16 * (J - 3) + q;
  const int J2 = j2_of_q(q);
  const int M1e = P.m1e[ki];
  const int nent = 2 * M1e + 2;               // even
  const float* vt = ws + P.voff[ki];
  const int Ncu = (32767 >> J) + 17;
  const int o0 = tile * TOUT;
  const int ub = (o0 - J2) * d - M1e;
  const int W = (TOUT - 1) * d + nent;
  const int PS = W + (((W - 1) >> J) << 1) + 4;   // plane stride (floats)
  const float* xb0 = x;
  const float* xb1 = x + T_LEN;
  // stage both planes; addr(s) = s + 2*(s>>J) (pad 2 floats per d; even-s b64
  // reads never straddle a pad since s stays even and d is even)
  for (int i = tid; i < W; i += 256) {
    int u = ub + i;
    bool ok = (unsigned)u < (unsigned)T_LEN;
    int uc = ok ? u : 0;
    float a = xb0[uc]; a = ok ? a : 0.f;
    float bv = xb1[uc]; bv = ok ? bv : 0.f;
    int ad = i + ((i >> J) << 1);
    xs[ad] = a; xs[PS + ad] = bv;
  }
  __syncthreads();
  int o = tid & (TOUT - 1);
  int b = (tid >> LT) & 1;
  int seg = tid >> (LT + 1);                   // [0, SPLIT)
  int per = ((nent >> 1) + SPLIT - 1) / SPLIT; // tap-pairs per segment
  int e_lo = 2 * per * seg; if (e_lo > nent) e_lo = nent;
  int e_hi = e_lo + 2 * per; if (e_hi > nent) e_hi = nent;
  const float* pl = xs + b * PS;
  int sb = o * d;                              // even
  float ar = 0.f, ai = 0.f;
  #pragma unroll 4
  for (int e = e_lo; e < e_hi; e += 2) {
    float4 v = *(const float4*)(vt + 2 * e);   // block-uniform broadcast
    int s = sb + e;
    float2 xv = *(const float2*)(pl + s + ((s >> J) << 1));
    ar += v.x * xv.x + v.z * xv.y;
    ai += v.y * xv.x + v.w * xv.y;
  }
  if (SPLIT > 1) {
    red[tid] = ar; red[256 + tid] = ai;
    __syncthreads();
    if (seg == 0) {
      #pragma unroll
      for (int ss = 1; ss < SPLIT; ++ss) {
        ar += red[tid + ss * TASKS];
        ai += red[256 + tid + ss * TASKS];
      }
    }
  }
  if (seg == 0 && o0 + o < Ncu) {
    int nidx = o0 + o;
    float ndf = (float)((nidx - J2) * d);
    float rev = ndf * exp2f(-(float)(16 * (J + 1) + q) * 0.0625f);
    rev -= floorf(rev);
    float sn, cs; __sincosf(rev * 6.28318530718f, &sn, &cs);
    float* ap = ws + P.ab[J - 3] + (q * 2) * Ncu * 2;
    *(float2*)(ap + 2 * (b * Ncu + nidx)) = make_float2(ar * cs - ai * sn, ar * sn + ai * cs);
  }
}

// direct exact conv for j<=2: thread -> 4 consecutive outputs; sliding 8-float
// register window; x via ds_read_b128; coalesced float4 store.
__device__ __forceinline__ void direct_path(const float* __restrict__ x,
                                            const float* __restrict__ fr,
                                            const float* __restrict__ fi,
                                            float* __restrict__ out, int Lmax,
                                            int rem, int tid,
                                            float* xs, float* red) {
  int b = rem / 1536;
  int r2 = rem - b * 1536;
  int k = r2 >> 5;
  int t0 = (r2 & 31) << 10;
  int j = k >> 4, q = k & 15;
  int M = (int)ceil(6.0 * exp2((double)j + (double)q * 0.0625)) + 2; // >= true M
  int P = Lmax >> 1;
  float* frs = red;            // 116 floats
  float* fis = red + 128;      // 116 floats
  int xlen = 1024 + 2 * M;
  const float* xb = x + b * T_LEN;
  for (int i = tid; i < xlen; i += 256) {
    int u = t0 - M + i;
    xs[i] = (u >= 0 && u < T_LEN) ? xb[u] : 0.f;
  }
  if (tid < 4) xs[xlen + tid] = 0.f;          // zero pad (overrun reads)
  const float* frk = fr + (size_t)k * Lmax + (P - M);
  const float* fik = fi + (size_t)k * Lmax + (P - M);
  int tl = 2 * M + 1;
  for (int i = tid; i < tl; i += 256) { frs[i] = frk[i]; fis[i] = fik[i]; }
  if (tid < 3) { frs[tl + tid] = 0.f; fis[tl + tid] = 0.f; }   // zero pad
  __syncthreads();
  float ar0 = 0.f, ar1 = 0.f, ar2 = 0.f, ar3 = 0.f;
  float ai0 = 0.f, ai1 = 0.f, ai2 = 0.f, ai3 = 0.f;
  const float4* xsv = (const float4*)(xs + 4 * tid);
  float4 w0 = xsv[0];
  int groups = (tl + 3) >> 2;
  for (int g = 0; g < groups; ++g) {
    float4 w1 = xsv[g + 1];
    float4 f4 = *(const float4*)(frs + 4 * g);
    float4 h4 = *(const float4*)(fis + 4 * g);
    ar0 += f4.x * w0.x + f4.y * w0.y + f4.z * w0.z + f4.w * w0.w;
    ai0 += h4.x * w0.x + h4.y * w0.y + h4.z * w0.z + h4.w * w0.w;
    ar1 += f4.x * w0.y + f4.y * w0.z + f4.z * w0.w + f4.w * w1.x;
    ai1 += h4.x * w0.y + h4.y * w0.z + h4.z * w0.w + h4.w * w1.x;
    ar2 += f4.x * w0.z + f4.y * w0.w + f4.z * w1.x + f4.w * w1.y;
    ai2 += h4.x * w0.z + h4.y * w0.w + h4.z * w1.x + h4.w * w1.y;
    ar3 += f4.x * w0.w + f4.y * w1.x + f4.z * w1.y + f4.w * w1.z;
    ai3 += h4.x * w0.w + h4.y * w1.x + h4.z * w1.y + h4.w * w1.z;
    w0 = w1;
  }
  size_t ob = (size_t)(b * NK + k) * T_LEN + t0 + 4 * tid;
  float4 res;
  res.x = sqrtf(ar0 * ar0 + ai0 * ai0);
  res.y = sqrtf(ar1 * ar1 + ai1 * ai1);
  res.z = sqrtf(ar2 * ar2 + ai2 * ai2);
  res.w = sqrtf(ar3 * ar3 + ai3 * ai3);
  *(float4*)(out + ob) = res;
}

__global__ __launch_bounds__(256) void k_s1(const float* __restrict__ x,
                                            const float* __restrict__ fr,
                                            const float* __restrict__ fi,
                                            float* __restrict__ out, int Lmax,
                                            float* __restrict__ ws, SParams P) {
  __shared__ __align__(16) float xs[12292];   // x window (8196) + v chunk (4096)
  __shared__ __align__(16) float red[512];
  int bx = blockIdx.x, tid = threadIdx.x;
  int o = 0;
  #pragma unroll
  for (int t = 1; t < 10; ++t) if (bx >= P.jb[t]) o = t;
  int rem = bx - P.jb[o];
  if (o == 9) { direct_path(x, fr, fi, out, Lmax, rem, tid, xs, red); return; }
  int j = 11 - o;
  int rc = rem >> 4, q = rem & 15;
  switch (j) {
    case 11: deep_path<11, 2, 2, 12>(x, ws, P, q, rc, tid, xs, red); break;
    case 10: deep_path<10, 3, 2, 6>(x, ws, P, q, rc, tid, xs, red); break;
    case 9:  deep_path<9, 4, 2, 3>(x, ws, P, q, rc, tid, xs, red); break;
    case 8:  deep_path<8, 8, 3, 1>(x, ws, P, q, rc, tid, xs, red); break;
    case 7:  deep_path<7, 16, 2, 1>(x, ws, P, q, rc, tid, xs, red); break;
    case 6:  small_path<6, 32, 5>(x, ws, P, q, rc, tid, xs, red); break;
    case 5:  small_path<5, 64, 6>(x, ws, P, q, rc, tid, xs, red); break;
    case 4:  small_path<4, 128, 7>(x, ws, P, q, rc, tid, xs, red); break;
    default: small_path<3, 128, 7>(x, ws, P, q, rc, tid, xs, red); break;
  }
}

// ---------------- stage 2: LDS-staged A, 8 outputs/thread ----------------
__global__ __launch_bounds__(256) void k_stage2(const float* __restrict__ ws,
                                                float* __restrict__ out, SParams P) {
  __shared__ __align__(16) float sA[8 * 48 * 2];   // 3 KB: (plane*4+seg) x 48 float2
  int k = KDIR + blockIdx.y;
  int j = k >> 4, q = k & 15;
  int d = 1 << j;
  int J2 = j2_of_q(q);
  int ntap = 2 * J2 + 1;
  float sig = 2.f * exp2f((float)(16 * j + q) * 0.0625f);
  float s2 = sig * 0.5f;
  int Ncu = (32767 >> j) + 17;
  const float* A0 = ws + P.ab[j - 3] + (q * 2) * Ncu * 2;
  const float* A1 = A0 + Ncu * 2;
  int bx = blockIdx.x, tid = threadIdx.x;
  int nbb = (bx << 8) >> j;                  // base n-index for segment 0
  int sstep = 8192 >> j;
  int Ci = (255 >> j) + ntap + 1;            // staged run length per segment
  #pragma unroll
  for (int pi = 0; pi < 8; ++pi) {
    int i = pi & 3, p = pi >> 2;
    const float* Ap = (p ? A1 : A0) + 2 * (nbb + i * sstep);
    for (int c = tid; c < Ci; c += 256)
      *(float2*)(sA + (pi * 48 + c) * 2) = *(const float2*)(Ap + 2 * c);
  }
  __syncthreads();
  int t0 = (bx << 8) + tid;                  // [0, 8192); outputs t0 + 8192*i
  int phi = t0 & (d - 1);
  int nl = (t0 >> j) - nbb;                  // local n offset within staged run
  float fd = (float)d;
  float inv2 = 1.f / (s2 * s2);
  float u0 = (float)(phi + J2 * d);
  float eg = __expf(-0.5f * u0 * u0 * inv2);
  float mf = __expf((fd * u0 - 0.5f * fd * fd) * inv2);
  float qf = __expf(-fd * fd * inv2);
  float Z = 0.f;
  float sr0 = 0.f, si0 = 0.f, sr1 = 0.f, si1 = 0.f;
  float sr2 = 0.f, si2 = 0.f, sr3 = 0.f, si3 = 0.f;
  float tr0 = 0.f, ti0 = 0.f, tr1 = 0.f, ti1 = 0.f;
  float tr2 = 0.f, ti2 = 0.f, tr3 = 0.f, ti3 = 0.f;
  const float* base = sA + 2 * nl;
  for (int rr = 0; rr < ntap; ++rr) {
    float w = eg; eg *= mf; mf *= qf; Z += w;
    float2 a0 = *(const float2*)(base + (0 * 48 + rr) * 2);
    float2 a1 = *(const float2*)(base + (1 * 48 + rr) * 2);
    float2 a2 = *(const float2*)(base + (2 * 48 + rr) * 2);
    float2 a3 = *(const float2*)(base + (3 * 48 + rr) * 2);
    float2 b0 = *(const float2*)(base + (4 * 48 + rr) * 2);
    float2 b1 = *(const float2*)(base + (5 * 48 + rr) * 2);
    float2 b2 = *(const float2*)(base + (6 * 48 + rr) * 2);
    float2 b3 = *(const float2*)(base + (7 * 48 + rr) * 2);
    sr0 += w * a0.x; si0 += w * a0.y; sr1 += w * a1.x; si1 += w * a1.y;
    sr2 += w * a2.x; si2 += w * a2.y; sr3 += w * a3.x; si3 += w * a3.y;
    tr0 += w * b0.x; ti0 += w * b0.y; tr1 += w * b1.x; ti1 += w * b1.y;
    tr2 += w * b2.x; ti2 += w * b2.y; tr3 += w * b3.x; ti3 += w * b3.y;
  }
  float zi = 1.f / Z;
  size_t ob0 = (size_t)k * T_LEN + t0;
  size_t ob1 = (size_t)(NK + k) * T_LEN + t0;
  out[ob0]         = sqrtf(sr0 * sr0 + si0 * si0) * zi;
  out[ob0 + 8192]  = sqrtf(sr1 * sr1 + si1 * si1) * zi;
  out[ob0 + 16384] = sqrtf(sr2 * sr2 + si2 * si2) * zi;
  out[ob0 + 24576] = sqrtf(sr3 * sr3 + si3 * si3) * zi;
  out[ob1]         = sqrtf(tr0 * tr0 + ti0 * ti0) * zi;
  out[ob1 + 8192]  = sqrtf(tr1 * tr1 + ti1 * ti1) * zi;
  out[ob1 + 16384] = sqrtf(tr2 * tr2 + ti2 * ti2) * zi;
  out[ob1 + 24576] = sqrtf(tr3 * tr3 + ti3 * ti3) * zi;
}

// ---------------- launch ----------------
extern "C" void kernel_launch(void* const* d_in, const int* in_sizes, int n_in,
                              void* d_out, int out_size, void* d_ws, size_t ws_size,
                              hipStream_t stream) {
  const float* x  = (const float*)d_in[0];
  const float* fr = (const float*)d_in[1];
  const float* fi = (const float*)d_in[2];
  float* out = (float*)d_out;
  float* ws  = (float*)d_ws;
  int Lmax = in_sizes[1] / NK;   // 47069

  // host-side geometry (pure CPU math, deterministic, graph-capture-safe)
  SParams Pm;
  int cur = 0, maxslot = 0;
  for (int ki = 0; ki < 144; ++ki) {
    int j = (ki + 48) >> 4, q = ki & 15;
    double sig = 2.0 * exp2(((double)(16 * j + q)) / 16.0);
    double s1 = sig * 0.86602540378443864676;
    int M1 = (int)ceil(3.5 * s1);
    int M1e = (M1 + 1) & ~1;
    int slotc = (2 * M1e + 2 + 511) & ~511;   // 512-granular
    Pm.m1e[ki] = M1e;
    Pm.slot[ki] = slotc;
    Pm.voff[ki] = cur;
    cur += 2 * slotc;
    if (slotc > maxslot) maxslot = slotc;
  }
  for (int j = 3; j <= 11; ++j) {
    Pm.ab[j - 3] = cur;
    cur += 32 * ((32767 >> j) + 17) * 2;   // 16q * 2b * Ncu * 2 words
  }
  // block ranges: j = 11 down to 3, then direct
  const int DG[5]  = {2, 3, 4, 8, 16};   // outputs per tile, j=11..7
  const int DCH[5] = {12, 6, 3, 1, 1};   // tap-chunks per tile (S*2048 taps)
  const int STO[4] = {32, 64, 128, 128}; // TOUT, j=6..3
  Pm.jb[0] = 0;
  for (int o = 0; o < 9; ++o) {
    int j = 11 - o;
    int Ncu = (32767 >> j) + 17;
    int cnt;
    if (o < 5) {
      int tiles = (Ncu + DG[o] - 1) / DG[o];
      cnt = tiles * DCH[o] * 16;
    } else {
      int TOUT = STO[o - 5];
      cnt = ((Ncu + TOUT - 1) / TOUT) * 16;
    }
    Pm.jb[o + 1] = Pm.jb[o] + cnt;
  }
  Pm.jb[10] = Pm.jb[9] + (T_LEN / 1024) * KDIR * NB;   // + direct blocks (3072)

  // zero the atomic arenas (j=9,10,11)
  int zbase = Pm.ab[6];
  int zn = (Pm.ab[8] + 32 * ((32767 >> 11) + 17) * 2) - zbase;   // 10240 words

  k_pre<<<dim3((maxslot + 1023) / 1024, 145), dim3(256), 0, stream>>>(ws, Pm, zbase, zn);
  k_s1<<<dim3(Pm.jb[10]), dim3(256), 0, stream>>>(x, fr, fi, out, Lmax, ws, Pm);
  k_stage2<<<dim3(T_LEN / (256 * 4), NK - KDIR), dim3(256), 0, stream>>>(ws, out, Pm);
}

// Round 6
// 229.910 us; speedup vs baseline: 1.1199x; 1.0168x over previous
//
#include <hip/hip_runtime.h>
#include <math.h>

// ---------------- problem constants ----------------
#define T_LEN   32768
#define NK      192
#define NB      2
#define KDIR    48            // k < KDIR (j<=2): exact direct conv path
#define MAXM    56            // max half-support for direct path (true max 48)

struct SParams {
  int m1e[144];   // even half-support of stage-1 kernel per k-48
  int slot[144];  // padded complex tap count per k-48 (mult of 512, zero tail)
  int voff[144];  // v-table word offset per k-48
  int ab[9];      // A-arena word base per octave j-3
  int jb[11];     // block-range bases: j=11..3 (9), direct, end
};

__device__ __forceinline__ int j2_of_q(int q) {
  // ceil(3.25 * 2^(q/16)) : {4,...,4,5,...,5,6,...,6,7}
  return 4 + (q >= 5) + (q >= 10) + (q >= 15);
}

// ---- k_pre: all v-tables (zero-filled tails) + zero atomic arenas ----
__global__ __launch_bounds__(256) void k_pre(float* __restrict__ ws, SParams P,
                                             int zbase, int zn) {
  int tid = threadIdx.x;
  if (blockIdx.y == 144) {
    int stride = gridDim.x * 256;
    for (int i = blockIdx.x * 256 + tid; i < zn; i += stride) ws[zbase + i] = 0.f;
    return;
  }
  int ki = blockIdx.y;                 // 0..143
  int slotc = P.slot[ki];
  int M1e = P.m1e[ki];
  float* dst = ws + P.voff[ki];
  int nent = 2 * M1e + 2;              // m in [-M1e, M1e+1]
  int k = ki + 48;
  int j = k >> 4, q = k & 15;
  float sig = 2.f * exp2f((float)(16 * j + q) * 0.0625f);
  float s1 = sig * 0.86602540378f;
  float gc = -0.5f / (s1 * s1);
  float om = 6.28318530718f / sig;
  float norm = 1.f / (2.50662827463f * s1 * erff((float)M1e / (1.41421356237f * s1)));
  #pragma unroll
  for (int e0 = 0; e0 < 4; ++e0) {
    int e = blockIdx.x * 1024 + e0 * 256 + tid;
    if (e >= slotc) continue;
    if (e >= nent) { dst[2 * e] = 0.f; dst[2 * e + 1] = 0.f; continue; }
    float mm = (float)(e - M1e);
    float g = __expf(gc * mm * mm) * norm;
    float sn, cs; __sincosf(om * mm, &sn, &cs);
    dst[2 * e] = g * cs;
    dst[2 * e + 1] = g * sn;
  }
}

// ================= stage 1 =================
// deep path (j=7..11): block = (j, q, output-tile, tap-chunk). x window staged
// in LDS; v read from global (L2-resident) with 1-deep register prefetch.
// small path (j=3..6): thread-per-(output,batch,tap-segment); v broadcast reads.
// direct path (j<=2): exact conv, merged as trailing block range.

template<int J, int G, int S, int CH>
__device__ __forceinline__ void deep_path(const float* __restrict__ x,
                                          float* __restrict__ ws, const SParams& P,
                                          int q, int rc, int tid,
                                          float* xs, float* red) {
  constexpr int d = 1 << J;
  constexpr int E = 2048;                    // taps per staged window
  const int tile = rc / CH;
  const int chunk = rc % CH;
  const int ki = 16 * (J - 3) + q;
  const int J2 = j2_of_q(q);
  const int slot = P.slot[ki];
  const int e_base = chunk * (S * E);
  if (e_base >= slot) return;                // empty chunk for this q
  const int M1e = P.m1e[ki];
  const float* vt = ws + P.voff[ki];
  const int n0 = tile * G;
  const int ubase0 = (n0 - J2) * d - M1e;    // u at e=0, g=0 (even)
  const float* xb0 = x;
  const float* xb1 = x + T_LEN;

  float acc[4 * G];
  #pragma unroll
  for (int i = 0; i < 4 * G; ++i) acc[i] = 0.f;

  #pragma unroll
  for (int s = 0; s < S; ++s) {
    int e0 = e_base + s * E;
    if (e0 >= slot) break;                   // uniform across block
    int Ech = slot - e0; if (Ech > E) Ech = E;   // multiple of 512
    int ub = ubase0 + e0;
    int Wn = Ech + (G - 1) * d + 2;
    if (ub < T_LEN && ub + Wn > 0) {         // window intersects signal (uniform)
      int Wh = (Wn + 1) >> 1;
      // stage x: xs float4 i = samples (2i, 2i+1) as (xa0, xb0, xa1, xb1)
      for (int i = tid; i < Wh; i += 256) {
        int u0 = ub + 2 * i;                    // even
        bool ok = (unsigned)u0 <= (unsigned)(T_LEN - 2);
        int uc = ok ? u0 : 0;
        float2 a = *(const float2*)(xb0 + uc);
        float2 b = *(const float2*)(xb1 + uc);
        float4 w;
        w.x = ok ? a.x : 0.f; w.y = ok ? b.x : 0.f;
        w.z = ok ? a.y : 0.f; w.w = ok ? b.y : 0.f;
        *(float4*)(xs + 4 * i) = w;
      }
      __syncthreads();
      int pend = Ech >> 9;                      // 512 taps per pass
      const float4* xp0 = (const float4*)xs + tid;
      const float* vte = vt + 2 * e0 + 4 * tid;
      float4 vp = *(const float4*)(vte);        // prefetch pass 0
      for (int ps = 0; ps < pend; ++ps) {
        float4 v = vp;
        if (ps + 1 < pend) vp = *(const float4*)(vte + ((ps + 1) << 10));
        const float4* xp = xp0 + (ps << 8);
        #pragma unroll
        for (int g = 0; g < G; ++g) {
          float4 xv = xp[g * (d >> 1)];
          acc[4 * g + 0] += v.x * xv.x + v.z * xv.z;   // ar0
          acc[4 * g + 1] += v.y * xv.x + v.w * xv.z;   // ai0
          acc[4 * g + 2] += v.x * xv.y + v.z * xv.w;   // ar1
          acc[4 * g + 3] += v.y * xv.y + v.w * xv.w;   // ai1
        }
      }
      __syncthreads();
    }
  }

  // block-wide reduction of 4G values
  #pragma unroll
  for (int st = 1; st < 64; st <<= 1) {
    #pragma unroll
    for (int i = 0; i < 4 * G; ++i) acc[i] += __shfl_xor(acc[i], st, 64);
  }
  int wv = tid >> 6;
  if ((tid & 63) == 0) {
    #pragma unroll
    for (int gg = 0; gg < G; ++gg)
      *(float4*)(red + wv * 64 + 4 * gg) =
        make_float4(acc[4 * gg], acc[4 * gg + 1], acc[4 * gg + 2], acc[4 * gg + 3]);
  }
  __syncthreads();
  if (tid < 4 * G)
    red[256 + tid] = red[tid] + red[64 + tid] + red[128 + tid] + red[192 + tid];
  __syncthreads();
  if (tid < G) {
    int nidx = n0 + tid;
    int Ncu = (32767 >> J) + 17;
    if (nidx < Ncu) {
      float ar0 = red[256 + 4 * tid], ai0 = red[256 + 4 * tid + 1];
      float ar1 = red[256 + 4 * tid + 2], ai1 = red[256 + 4 * tid + 3];
      float ndf = (float)((nidx - J2) * d);
      float rev = ndf * exp2f(-(float)(16 * (J + 1) + q) * 0.0625f);
      rev -= floorf(rev);
      float sn, cs; __sincosf(rev * 6.28318530718f, &sn, &cs);
      float* ap = ws + P.ab[J - 3] + (q * 2) * Ncu * 2;
      float r0 = ar0 * cs - ai0 * sn, i0 = ar0 * sn + ai0 * cs;
      float r1 = ar1 * cs - ai1 * sn, i1 = ar1 * sn + ai1 * cs;
      if (CH == 1) {
        *(float2*)(ap + 2 * nidx) = make_float2(r0, i0);
        *(float2*)(ap + 2 * (Ncu + nidx)) = make_float2(r1, i1);
      } else {
        atomicAdd(ap + 2 * nidx, r0);
        atomicAdd(ap + 2 * nidx + 1, i0);
        atomicAdd(ap + 2 * (Ncu + nidx), r1);
        atomicAdd(ap + 2 * (Ncu + nidx) + 1, i1);
      }
    }
  }
}

template<int J, int TOUT, int LT>
__device__ __forceinline__ void small_path(const float* __restrict__ x,
                                           float* __restrict__ ws, const SParams& P,
                                           int q, int tile, int tid,
                                           float* xs, float* red) {
  constexpr int d = 1 << J;
  constexpr int TASKS = TOUT * 2;
  constexpr int SPLIT = 256 / TASKS;
  const int ki = 16 * (J - 3) + q;
  const int J2 = j2_of_q(q);
  const int M1e = P.m1e[ki];
  const int nent = 2 * M1e + 2;               // even
  const float* vt = ws + P.voff[ki];
  const int Ncu = (32767 >> J) + 17;
  const int o0 = tile * TOUT;
  const int ub = (o0 - J2) * d - M1e;
  const int W = (TOUT - 1) * d + nent;
  const int PS = W + (((W - 1) >> J) << 1) + 4;   // plane stride (floats)
  const float* xb0 = x;
  const float* xb1 = x + T_LEN;
  // stage both planes; addr(s) = s + 2*(s>>J) (pad 2 floats per d; even-s b64
  // reads never straddle a pad since s stays even and d is even)
  for (int i = tid; i < W; i += 256) {
    int u = ub + i;
    bool ok = (unsigned)u < (unsigned)T_LEN;
    int uc = ok ? u : 0;
    float a = xb0[uc]; a = ok ? a : 0.f;
    float bv = xb1[uc]; bv = ok ? bv : 0.f;
    int ad = i + ((i >> J) << 1);
    xs[ad] = a; xs[PS + ad] = bv;
  }
  __syncthreads();
  int o = tid & (TOUT - 1);
  int b = (tid >> LT) & 1;
  int seg = tid >> (LT + 1);                   // [0, SPLIT)
  int per = ((nent >> 1) + SPLIT - 1) / SPLIT; // tap-pairs per segment
  int e_lo = 2 * per * seg; if (e_lo > nent) e_lo = nent;
  int e_hi = e_lo + 2 * per; if (e_hi > nent) e_hi = nent;
  const float* pl = xs + b * PS;
  int sb = o * d;                              // even
  float ar = 0.f, ai = 0.f;
  #pragma unroll 4
  for (int e = e_lo; e < e_hi; e += 2) {
    float4 v = *(const float4*)(vt + 2 * e);   // block-uniform broadcast
    int s = sb + e;
    float2 xv = *(const float2*)(pl + s + ((s >> J) << 1));
    ar += v.x * xv.x + v.z * xv.y;
    ai += v.y * xv.x + v.w * xv.y;
  }
  if (SPLIT > 1) {
    red[tid] = ar; red[256 + tid] = ai;
    __syncthreads();
    if (seg == 0) {
      #pragma unroll
      for (int ss = 1; ss < SPLIT; ++ss) {
        ar += red[tid + ss * TASKS];
        ai += red[256 + tid + ss * TASKS];
      }
    }
  }
  if (seg == 0 && o0 + o < Ncu) {
    int nidx = o0 + o;
    float ndf = (float)((nidx - J2) * d);
    float rev = ndf * exp2f(-(float)(16 * (J + 1) + q) * 0.0625f);
    rev -= floorf(rev);
    float sn, cs; __sincosf(rev * 6.28318530718f, &sn, &cs);
    float* ap = ws + P.ab[J - 3] + (q * 2) * Ncu * 2;
    *(float2*)(ap + 2 * (b * Ncu + nidx)) = make_float2(ar * cs - ai * sn, ar * sn + ai * cs);
  }
}

// direct exact conv for j<=2: thread -> 4 consecutive outputs; sliding 8-float
// register window; x via ds_read_b128; coalesced float4 store.
__device__ __forceinline__ void direct_path(const float* __restrict__ x,
                                            const float* __restrict__ fr,
                                            const float* __restrict__ fi,
                                            float* __restrict__ out, int Lmax,
                                            int rem, int tid,
                                            float* xs, float* red) {
  int b = rem / 1536;
  int r2 = rem - b * 1536;
  int k = r2 >> 5;
  int t0 = (r2 & 31) << 10;
  int j = k >> 4, q = k & 15;
  int M = (int)ceil(6.0 * exp2((double)j + (double)q * 0.0625)) + 2; // >= true M
  int P = Lmax >> 1;
  float* frs = red;            // 116 floats
  float* fis = red + 128;      // 116 floats
  int xlen = 1024 + 2 * M;
  const float* xb = x + b * T_LEN;
  for (int i = tid; i < xlen; i += 256) {
    int u = t0 - M + i;
    xs[i] = (u >= 0 && u < T_LEN) ? xb[u] : 0.f;
  }
  if (tid < 4) xs[xlen + tid] = 0.f;          // zero pad (overrun reads)
  const float* frk = fr + (size_t)k * Lmax + (P - M);
  const float* fik = fi + (size_t)k * Lmax + (P - M);
  int tl = 2 * M + 1;
  for (int i = tid; i < tl; i += 256) { frs[i] = frk[i]; fis[i] = fik[i]; }
  if (tid < 3) { frs[tl + tid] = 0.f; fis[tl + tid] = 0.f; }   // zero pad
  __syncthreads();
  float ar0 = 0.f, ar1 = 0.f, ar2 = 0.f, ar3 = 0.f;
  float ai0 = 0.f, ai1 = 0.f, ai2 = 0.f, ai3 = 0.f;
  const float4* xsv = (const float4*)(xs + 4 * tid);
  float4 w0 = xsv[0];
  int groups = (tl + 3) >> 2;
  for (int g = 0; g < groups; ++g) {
    float4 w1 = xsv[g + 1];
    float4 f4 = *(const float4*)(frs + 4 * g);
    float4 h4 = *(const float4*)(fis + 4 * g);
    ar0 += f4.x * w0.x + f4.y * w0.y + f4.z * w0.z + f4.w * w0.w;
    ai0 += h4.x * w0.x + h4.y * w0.y + h4.z * w0.z + h4.w * w0.w;
    ar1 += f4.x * w0.y + f4.y * w0.z + f4.z * w0.w + f4.w * w1.x;
    ai1 += h4.x * w0.y + h4.y * w0.z + h4.z * w0.w + h4.w * w1.x;
    ar2 += f4.x * w0.z + f4.y * w0.w + f4.z * w1.x + f4.w * w1.y;
    ai2 += h4.x * w0.z + h4.y * w0.w + h4.z * w1.x + h4.w * w1.y;
    ar3 += f4.x * w0.w + f4.y * w1.x + f4.z * w1.y + f4.w * w1.z;
    ai3 += h4.x * w0.w + h4.y * w1.x + h4.z * w1.y + h4.w * w1.z;
    w0 = w1;
  }
  size_t ob = (size_t)(b * NK + k) * T_LEN + t0 + 4 * tid;
  float4 res;
  res.x = sqrtf(ar0 * ar0 + ai0 * ai0);
  res.y = sqrtf(ar1 * ar1 + ai1 * ai1);
  res.z = sqrtf(ar2 * ar2 + ai2 * ai2);
  res.w = sqrtf(ar3 * ar3 + ai3 * ai3);
  *(float4*)(out + ob) = res;
}

__global__ __launch_bounds__(256) void k_s1(const float* __restrict__ x,
                                            const float* __restrict__ fr,
                                            const float* __restrict__ fi,
                                            float* __restrict__ out, int Lmax,
                                            float* __restrict__ ws, SParams P) {
  __shared__ __align__(16) float xs[8200];    // 32.8 KB -> 4 blocks/CU
  __shared__ __align__(16) float red[512];
  int bx = blockIdx.x, tid = threadIdx.x;
  int o = 0;
  #pragma unroll
  for (int t = 1; t < 10; ++t) if (bx >= P.jb[t]) o = t;
  int rem = bx - P.jb[o];
  if (o == 9) { direct_path(x, fr, fi, out, Lmax, rem, tid, xs, red); return; }
  int j = 11 - o;
  int rc = rem >> 4, q = rem & 15;
  switch (j) {
    case 11: deep_path<11, 2, 3, 8>(x, ws, P, q, rc, tid, xs, red); break;
    case 10: deep_path<10, 3, 3, 4>(x, ws, P, q, rc, tid, xs, red); break;
    case 9:  deep_path<9, 4, 3, 2>(x, ws, P, q, rc, tid, xs, red); break;
    case 8:  deep_path<8, 8, 3, 1>(x, ws, P, q, rc, tid, xs, red); break;
    case 7:  deep_path<7, 16, 2, 1>(x, ws, P, q, rc, tid, xs, red); break;
    case 6:  small_path<6, 32, 5>(x, ws, P, q, rc, tid, xs, red); break;
    case 5:  small_path<5, 64, 6>(x, ws, P, q, rc, tid, xs, red); break;
    case 4:  small_path<4, 128, 7>(x, ws, P, q, rc, tid, xs, red); break;
    default: small_path<3, 128, 7>(x, ws, P, q, rc, tid, xs, red); break;
  }
}

// ---------------- stage 2: 2 k's per block, LDS-staged A ----------------
__global__ __launch_bounds__(256) void k_stage2(const float* __restrict__ ws,
                                                float* __restrict__ out, SParams P) {
  __shared__ __align__(16) float sA[2][8][48][2];   // 6 KB
  int by = blockIdx.y;                 // 0..71 -> k pair (KDIR+2by, +1), same j
  int bx = blockIdx.x, tid = threadIdx.x;
  int k0 = KDIR + 2 * by;
  int j = k0 >> 4;
  int d = 1 << j;
  int Ncu = (32767 >> j) + 17;
  int nbb = (bx << 8) >> j;                  // base n-index for segment 0
  int sstep = 8192 >> j;
  #pragma unroll
  for (int kk = 0; kk < 2; ++kk) {
    int q = (k0 + kk) & 15;
    int ntap = 2 * j2_of_q(q) + 1;
    const float* A0 = ws + P.ab[j - 3] + (q * 2) * Ncu * 2;
    int Ci = (255 >> j) + ntap + 1;          // staged run length per segment
    #pragma unroll
    for (int pi = 0; pi < 8; ++pi) {
      int i = pi & 3, p = pi >> 2;
      const float* Ap = A0 + p * Ncu * 2 + 2 * (nbb + i * sstep);
      for (int c = tid; c < Ci; c += 256)
        *(float2*)(&sA[kk][pi][c][0]) = *(const float2*)(Ap + 2 * c);
    }
  }
  __syncthreads();
  int t0 = (bx << 8) + tid;                  // [0, 8192); outputs t0 + 8192*i
  int phi = t0 & (d - 1);
  int nl = (t0 >> j) - nbb;                  // local n offset within staged run
  float fd = (float)d;
  #pragma unroll
  for (int kk = 0; kk < 2; ++kk) {
    int k = k0 + kk, q = k & 15;
    int J2 = j2_of_q(q);
    int ntap = 2 * J2 + 1;
    float sig = 2.f * exp2f((float)(16 * j + q) * 0.0625f);
    float s2 = sig * 0.5f;
    float inv2 = 1.f / (s2 * s2);
    float u0 = (float)(phi + J2 * d);
    float eg = __expf(-0.5f * u0 * u0 * inv2);
    float mf = __expf((fd * u0 - 0.5f * fd * fd) * inv2);
    float qf = __expf(-fd * fd * inv2);
    float Z = 0.f;
    float sr0 = 0.f, si0 = 0.f, sr1 = 0.f, si1 = 0.f;
    float sr2 = 0.f, si2 = 0.f, sr3 = 0.f, si3 = 0.f;
    float tr0 = 0.f, ti0 = 0.f, tr1 = 0.f, ti1 = 0.f;
    float tr2 = 0.f, ti2 = 0.f, tr3 = 0.f, ti3 = 0.f;
    const float* base = &sA[kk][0][nl][0];
    for (int rr = 0; rr < ntap; ++rr) {
      float w = eg; eg *= mf; mf *= qf; Z += w;
      float2 a0 = *(const float2*)(base + (0 * 48 + rr) * 2);
      float2 a1 = *(const float2*)(base + (1 * 48 + rr) * 2);
      float2 a2 = *(const float2*)(base + (2 * 48 + rr) * 2);
      float2 a3 = *(const float2*)(base + (3 * 48 + rr) * 2);
      float2 b0 = *(const float2*)(base + (4 * 48 + rr) * 2);
      float2 b1 = *(const float2*)(base + (5 * 48 + rr) * 2);
      float2 b2 = *(const float2*)(base + (6 * 48 + rr) * 2);
      float2 b3 = *(const float2*)(base + (7 * 48 + rr) * 2);
      sr0 += w * a0.x; si0 += w * a0.y; sr1 += w * a1.x; si1 += w * a1.y;
      sr2 += w * a2.x; si2 += w * a2.y; sr3 += w * a3.x; si3 += w * a3.y;
      tr0 += w * b0.x; ti0 += w * b0.y; tr1 += w * b1.x; ti1 += w * b1.y;
      tr2 += w * b2.x; ti2 += w * b2.y; tr3 += w * b3.x; ti3 += w * b3.y;
    }
    float zi = 1.f / Z;
    size_t ob0 = (size_t)k * T_LEN + t0;
    size_t ob1 = (size_t)(NK + k) * T_LEN + t0;
    out[ob0]         = sqrtf(sr0 * sr0 + si0 * si0) * zi;
    out[ob0 + 8192]  = sqrtf(sr1 * sr1 + si1 * si1) * zi;
    out[ob0 + 16384] = sqrtf(sr2 * sr2 + si2 * si2) * zi;
    out[ob0 + 24576] = sqrtf(sr3 * sr3 + si3 * si3) * zi;
    out[ob1]         = sqrtf(tr0 * tr0 + ti0 * ti0) * zi;
    out[ob1 + 8192]  = sqrtf(tr1 * tr1 + ti1 * ti1) * zi;
    out[ob1 + 16384] = sqrtf(tr2 * tr2 + ti2 * ti2) * zi;
    out[ob1 + 24576] = sqrtf(tr3 * tr3 + ti3 * ti3) * zi;
  }
}

// ---------------- launch ----------------
extern "C" void kernel_launch(void* const* d_in, const int* in_sizes, int n_in,
                              void* d_out, int out_size, void* d_ws, size_t ws_size,
                              hipStream_t stream) {
  const float* x  = (const float*)d_in[0];
  const float* fr = (const float*)d_in[1];
  const float* fi = (const float*)d_in[2];
  float* out = (float*)d_out;
  float* ws  = (float*)d_ws;
  int Lmax = in_sizes[1] / NK;   // 47069

  // host-side geometry (pure CPU math, deterministic, graph-capture-safe)
  SParams Pm;
  int cur = 0, maxslot = 0;
  for (int ki = 0; ki < 144; ++ki) {
    int j = (ki + 48) >> 4, q = ki & 15;
    double sig = 2.0 * exp2(((double)(16 * j + q)) / 16.0);
    double s1 = sig * 0.86602540378443864676;
    int M1 = (int)ceil(3.5 * s1);
    int M1e = (M1 + 1) & ~1;
    int slotc = (2 * M1e + 2 + 511) & ~511;   // 512-granular
    Pm.m1e[ki] = M1e;
    Pm.slot[ki] = slotc;
    Pm.voff[ki] = cur;
    cur += 2 * slotc;
    if (slotc > maxslot) maxslot = slotc;
  }
  for (int j = 3; j <= 11; ++j) {
    Pm.ab[j - 3] = cur;
    cur += 32 * ((32767 >> j) + 17) * 2;   // 16q * 2b * Ncu * 2 words
  }
  // block ranges: j = 11 down to 3, then direct
  const int DG[5]  = {2, 3, 4, 8, 16};   // outputs per tile, j=11..7
  const int DCH[5] = {8, 4, 2, 1, 1};    // tap-chunks per tile (S*2048 taps each)
  const int STO[4] = {32, 64, 128, 128}; // TOUT, j=6..3
  Pm.jb[0] = 0;
  for (int o = 0; o < 9; ++o) {
    int j = 11 - o;
    int Ncu = (32767 >> j) + 17;
    int cnt;
    if (o < 5) {
      int tiles = (Ncu + DG[o] - 1) / DG[o];
      cnt = tiles * DCH[o] * 16;
    } else {
      int TOUT = STO[o - 5];
      cnt = ((Ncu + TOUT - 1) / TOUT) * 16;
    }
    Pm.jb[o + 1] = Pm.jb[o] + cnt;
  }
  Pm.jb[10] = Pm.jb[9] + (T_LEN / 1024) * KDIR * NB;   // + direct blocks (3072)

  // zero the atomic arenas (j=9,10,11)
  int zbase = Pm.ab[6];
  int zn = (Pm.ab[8] + 32 * ((32767 >> 11) + 17) * 2) - zbase;   // 10240 words

  k_pre<<<dim3((maxslot + 1023) / 1024, 145), dim3(256), 0, stream>>>(ws, Pm, zbase, zn);
  k_s1<<<dim3(Pm.jb[10]), dim3(256), 0, stream>>>(x, fr, fi, out, Lmax, ws, Pm);
  k_stage2<<<dim3(T_LEN / (256 * 4), (NK - KDIR) / 2), dim3(256), 0, stream>>>(ws, out, Pm);
}

// Round 7
// 227.375 us; speedup vs baseline: 1.1324x; 1.0111x over previous
//
#include <hip/hip_runtime.h>
#include <math.h>

// ---------------- problem constants ----------------
#define T_LEN   32768
#define NK      192
#define NB      2
#define KDIR    48            // k < KDIR (j<=2): exact direct conv path
#define MAXM    56            // max half-support for direct path (true max 48)

struct SParams {
  int m1e[144];   // even half-support of stage-1 kernel per k-48
  int slot[144];  // padded complex tap count per k-48 (mult of 512, zero tail)
  int voff[144];  // v-table word offset per k-48
  int ab[9];      // A-arena word base per octave j-3
  int jb[11];     // block-range bases: j=11..3 (9), direct, end
};

__device__ __forceinline__ int j2_of_q(int q) {
  // ceil(3.25 * 2^(q/16)) : {4,...,4,5,...,5,6,...,6,7}
  return 4 + (q >= 5) + (q >= 10) + (q >= 15);
}

// ---- k_pre: all v-tables (zero-filled tails) + zero atomic arenas ----
__global__ __launch_bounds__(256) void k_pre(float* __restrict__ ws, SParams P,
                                             int zbase, int zn) {
  int tid = threadIdx.x;
  if (blockIdx.y == 144) {
    int stride = gridDim.x * 256;
    for (int i = blockIdx.x * 256 + tid; i < zn; i += stride) ws[zbase + i] = 0.f;
    return;
  }
  int ki = blockIdx.y;                 // 0..143
  int slotc = P.slot[ki];
  int M1e = P.m1e[ki];
  float* dst = ws + P.voff[ki];
  int nent = 2 * M1e + 2;              // m in [-M1e, M1e+1]
  int k = ki + 48;
  int j = k >> 4, q = k & 15;
  float sig = 2.f * exp2f((float)(16 * j + q) * 0.0625f);
  float s1 = sig * 0.86602540378f;
  float gc = -0.5f / (s1 * s1);
  float om = 6.28318530718f / sig;
  float norm = 1.f / (2.50662827463f * s1 * erff((float)M1e / (1.41421356237f * s1)));
  #pragma unroll
  for (int e0 = 0; e0 < 4; ++e0) {
    int e = blockIdx.x * 1024 + e0 * 256 + tid;
    if (e >= slotc) continue;
    if (e >= nent) { dst[2 * e] = 0.f; dst[2 * e + 1] = 0.f; continue; }
    float mm = (float)(e - M1e);
    float g = __expf(gc * mm * mm) * norm;
    float sn, cs; __sincosf(om * mm, &sn, &cs);
    dst[2 * e] = g * cs;
    dst[2 * e + 1] = g * sn;
  }
}

// ================= stage 1 =================
// reg path (j=10,11): block = (q, tile, chunk). NO LDS: x straight from L2
// (interior passes clamp-free, uniform branch), v prefetched 1-deep. The
// x-window reuse at these d is ~1, so LDS staging was pure overhead.
// deep path (j=7..9): x staged in LDS (reuse 2.3-8.3x), v global prefetched.
// small path (j=3..6): thread-per-(output,batch,tap-segment); v broadcast.
// direct path (j<=2): exact conv, merged as trailing block range.

template<int J, int G, int CH>
__device__ __forceinline__ void reg_path(const float* __restrict__ x,
                                         float* __restrict__ ws, const SParams& P,
                                         int q, int rc, int tid, float* red) {
  constexpr int d = 1 << J;
  const int tile = rc / CH;
  const int chunk = rc % CH;
  const int ki = 16 * (J - 3) + q;
  const int J2 = j2_of_q(q);
  const int slot = P.slot[ki];
  const int per = ((slot + CH - 1) / CH + 511) & ~511;
  const int c0 = chunk * per;
  if (c0 >= slot) return;
  int c1 = c0 + per; if (c1 > slot) c1 = slot;
  const int M1e = P.m1e[ki];
  const float* vt = ws + P.voff[ki];
  const int n0 = tile * G;
  const int ub0 = (n0 - J2) * d - M1e + c0;   // even
  const float* xb0 = x;
  const float* xb1 = x + T_LEN;

  float acc[4 * G];
  #pragma unroll
  for (int i = 0; i < 4 * G; ++i) acc[i] = 0.f;

  int npass = (c1 - c0) >> 9;
  const float* vte = vt + 2 * c0 + 4 * tid;
  const int hi_lim = T_LEN - 512 - (G - 1) * d;  // interior iff ub in [0, hi_lim]
  float4 vp = *(const float4*)vte;               // prefetch pass 0
  for (int p = 0; p < npass; ++p) {
    float4 v = vp;
    if (p + 1 < npass) vp = *(const float4*)(vte + ((p + 1) << 10));
    int ub = ub0 + (p << 9);
    int u = ub + 2 * tid;
    if (ub >= 0 && ub <= hi_lim) {
      // interior: no bounds checks
      #pragma unroll
      for (int g = 0; g < G; ++g) {
        float2 a = *(const float2*)(xb0 + u + g * d);
        float2 b = *(const float2*)(xb1 + u + g * d);
        acc[4 * g + 0] += v.x * a.x + v.z * a.y;
        acc[4 * g + 1] += v.y * a.x + v.w * a.y;
        acc[4 * g + 2] += v.x * b.x + v.z * b.y;
        acc[4 * g + 3] += v.y * b.x + v.w * b.y;
      }
    } else if (ub < T_LEN && ub + 512 + (G - 1) * d > 0) {
      // edge pass: clamped
      #pragma unroll
      for (int g = 0; g < G; ++g) {
        int ug = u + g * d;
        int uc = min(max(ug, 0), T_LEN - 2);
        float2 a = *(const float2*)(xb0 + uc);
        float2 b = *(const float2*)(xb1 + uc);
        bool ok = (unsigned)ug <= (unsigned)(T_LEN - 2);
        float ax = ok ? a.x : 0.f, ay = ok ? a.y : 0.f;
        float bx = ok ? b.x : 0.f, by = ok ? b.y : 0.f;
        acc[4 * g + 0] += v.x * ax + v.z * ay;
        acc[4 * g + 1] += v.y * ax + v.w * ay;
        acc[4 * g + 2] += v.x * bx + v.z * by;
        acc[4 * g + 3] += v.y * bx + v.w * by;
      }
    }
  }

  // block-wide reduction of 4G values
  #pragma unroll
  for (int st = 1; st < 64; st <<= 1) {
    #pragma unroll
    for (int i = 0; i < 4 * G; ++i) acc[i] += __shfl_xor(acc[i], st, 64);
  }
  int wv = tid >> 6;
  if ((tid & 63) == 0) {
    #pragma unroll
    for (int gg = 0; gg < G; ++gg)
      *(float4*)(red + wv * 64 + 4 * gg) =
        make_float4(acc[4 * gg], acc[4 * gg + 1], acc[4 * gg + 2], acc[4 * gg + 3]);
  }
  __syncthreads();
  if (tid < 4 * G)
    red[256 + tid] = red[tid] + red[64 + tid] + red[128 + tid] + red[192 + tid];
  __syncthreads();
  if (tid < G) {
    int nidx = n0 + tid;
    int Ncu = (32767 >> J) + 17;
    if (nidx < Ncu) {
      float ar0 = red[256 + 4 * tid], ai0 = red[256 + 4 * tid + 1];
      float ar1 = red[256 + 4 * tid + 2], ai1 = red[256 + 4 * tid + 3];
      float ndf = (float)((nidx - J2) * d);
      float rev = ndf * exp2f(-(float)(16 * (J + 1) + q) * 0.0625f);
      rev -= floorf(rev);
      float sn, cs; __sincosf(rev * 6.28318530718f, &sn, &cs);
      float* ap = ws + P.ab[J - 3] + (q * 2) * Ncu * 2;
      float r0 = ar0 * cs - ai0 * sn, i0 = ar0 * sn + ai0 * cs;
      float r1 = ar1 * cs - ai1 * sn, i1 = ar1 * sn + ai1 * cs;
      atomicAdd(ap + 2 * nidx, r0);
      atomicAdd(ap + 2 * nidx + 1, i0);
      atomicAdd(ap + 2 * (Ncu + nidx), r1);
      atomicAdd(ap + 2 * (Ncu + nidx) + 1, i1);
    }
  }
}

template<int J, int G, int S, int CH, int E>
__device__ __forceinline__ void deep_path(const float* __restrict__ x,
                                          float* __restrict__ ws, const SParams& P,
                                          int q, int rc, int tid,
                                          float* xs, float* red) {
  constexpr int d = 1 << J;
  const int tile = rc / CH;
  const int chunk = rc % CH;
  const int ki = 16 * (J - 3) + q;
  const int J2 = j2_of_q(q);
  const int slot = P.slot[ki];
  const int e_base = chunk * (S * E);
  if (e_base >= slot) return;                // empty chunk for this q
  const int M1e = P.m1e[ki];
  const float* vt = ws + P.voff[ki];
  const int n0 = tile * G;
  const int ubase0 = (n0 - J2) * d - M1e;    // u at e=0, g=0 (even)
  const float* xb0 = x;
  const float* xb1 = x + T_LEN;

  float acc[4 * G];
  #pragma unroll
  for (int i = 0; i < 4 * G; ++i) acc[i] = 0.f;

  #pragma unroll
  for (int s = 0; s < S; ++s) {
    int e0 = e_base + s * E;
    if (e0 >= slot) break;                   // uniform across block
    int Ech = slot - e0; if (Ech > E) Ech = E;   // multiple of 512
    int ub = ubase0 + e0;
    int Wn = Ech + (G - 1) * d + 2;
    if (ub < T_LEN && ub + Wn > 0) {         // window intersects signal (uniform)
      int Wh = (Wn + 1) >> 1;
      // stage x: xs float4 i = samples (2i, 2i+1) as (xa0, xb0, xa1, xb1)
      for (int i = tid; i < Wh; i += 256) {
        int u0 = ub + 2 * i;                    // even
        bool ok = (unsigned)u0 <= (unsigned)(T_LEN - 2);
        int uc = ok ? u0 : 0;
        float2 a = *(const float2*)(xb0 + uc);
        float2 b = *(const float2*)(xb1 + uc);
        float4 w;
        w.x = ok ? a.x : 0.f; w.y = ok ? b.x : 0.f;
        w.z = ok ? a.y : 0.f; w.w = ok ? b.y : 0.f;
        *(float4*)(xs + 4 * i) = w;
      }
      __syncthreads();
      int pend = Ech >> 9;                      // 512 taps per pass
      const float4* xp0 = (const float4*)xs + tid;
      const float* vte = vt + 2 * e0 + 4 * tid;
      float4 vp = *(const float4*)(vte);        // prefetch pass 0
      for (int ps = 0; ps < pend; ++ps) {
        float4 v = vp;
        if (ps + 1 < pend) vp = *(const float4*)(vte + ((ps + 1) << 10));
        const float4* xp = xp0 + (ps << 8);
        #pragma unroll
        for (int g = 0; g < G; ++g) {
          float4 xv = xp[g * (d >> 1)];
          acc[4 * g + 0] += v.x * xv.x + v.z * xv.z;   // ar0
          acc[4 * g + 1] += v.y * xv.x + v.w * xv.z;   // ai0
          acc[4 * g + 2] += v.x * xv.y + v.z * xv.w;   // ar1
          acc[4 * g + 3] += v.y * xv.y + v.w * xv.w;   // ai1
        }
      }
      __syncthreads();
    }
  }

  // block-wide reduction of 4G values
  #pragma unroll
  for (int st = 1; st < 64; st <<= 1) {
    #pragma unroll
    for (int i = 0; i < 4 * G; ++i) acc[i] += __shfl_xor(acc[i], st, 64);
  }
  int wv = tid >> 6;
  if ((tid & 63) == 0) {
    #pragma unroll
    for (int gg = 0; gg < G; ++gg)
      *(float4*)(red + wv * 64 + 4 * gg) =
        make_float4(acc[4 * gg], acc[4 * gg + 1], acc[4 * gg + 2], acc[4 * gg + 3]);
  }
  __syncthreads();
  if (tid < 4 * G)
    red[256 + tid] = red[tid] + red[64 + tid] + red[128 + tid] + red[192 + tid];
  __syncthreads();
  if (tid < G) {
    int nidx = n0 + tid;
    int Ncu = (32767 >> J) + 17;
    if (nidx < Ncu) {
      float ar0 = red[256 + 4 * tid], ai0 = red[256 + 4 * tid + 1];
      float ar1 = red[256 + 4 * tid + 2], ai1 = red[256 + 4 * tid + 3];
      float ndf = (float)((nidx - J2) * d);
      float rev = ndf * exp2f(-(float)(16 * (J + 1) + q) * 0.0625f);
      rev -= floorf(rev);
      float sn, cs; __sincosf(rev * 6.28318530718f, &sn, &cs);
      float* ap = ws + P.ab[J - 3] + (q * 2) * Ncu * 2;
      float r0 = ar0 * cs - ai0 * sn, i0 = ar0 * sn + ai0 * cs;
      float r1 = ar1 * cs - ai1 * sn, i1 = ar1 * sn + ai1 * cs;
      if (CH == 1) {
        *(float2*)(ap + 2 * nidx) = make_float2(r0, i0);
        *(float2*)(ap + 2 * (Ncu + nidx)) = make_float2(r1, i1);
      } else {
        atomicAdd(ap + 2 * nidx, r0);
        atomicAdd(ap + 2 * nidx + 1, i0);
        atomicAdd(ap + 2 * (Ncu + nidx), r1);
        atomicAdd(ap + 2 * (Ncu + nidx) + 1, i1);
      }
    }
  }
}

template<int J, int TOUT, int LT>
__device__ __forceinline__ void small_path(const float* __restrict__ x,
                                           float* __restrict__ ws, const SParams& P,
                                           int q, int tile, int tid,
                                           float* xs, float* red) {
  constexpr int d = 1 << J;
  constexpr int TASKS = TOUT * 2;
  constexpr int SPLIT = 256 / TASKS;
  const int ki = 16 * (J - 3) + q;
  const int J2 = j2_of_q(q);
  const int M1e = P.m1e[ki];
  const int nent = 2 * M1e + 2;               // even
  const float* vt = ws + P.voff[ki];
  const int Ncu = (32767 >> J) + 17;
  const int o0 = tile * TOUT;
  const int ub = (o0 - J2) * d - M1e;
  const int W = (TOUT - 1) * d + nent;
  const int PS = W + (((W - 1) >> J) << 1) + 4;   // plane stride (floats)
  const float* xb0 = x;
  const float* xb1 = x + T_LEN;
  // stage both planes; addr(s) = s + 2*(s>>J) (pad 2 floats per d; even-s b64
  // reads never straddle a pad since s stays even and d is even)
  for (int i = tid; i < W; i += 256) {
    int u = ub + i;
    bool ok = (unsigned)u < (unsigned)T_LEN;
    int uc = ok ? u : 0;
    float a = xb0[uc]; a = ok ? a : 0.f;
    float bv = xb1[uc]; bv = ok ? bv : 0.f;
    int ad = i + ((i >> J) << 1);
    xs[ad] = a; xs[PS + ad] = bv;
  }
  __syncthreads();
  int o = tid & (TOUT - 1);
  int b = (tid >> LT) & 1;
  int seg = tid >> (LT + 1);                   // [0, SPLIT)
  int per = ((nent >> 1) + SPLIT - 1) / SPLIT; // tap-pairs per segment
  int e_lo = 2 * per * seg; if (e_lo > nent) e_lo = nent;
  int e_hi = e_lo + 2 * per; if (e_hi > nent) e_hi = nent;
  const float* pl = xs + b * PS;
  int sb = o * d;                              // even
  float ar = 0.f, ai = 0.f;
  #pragma unroll 4
  for (int e = e_lo; e < e_hi; e += 2) {
    float4 v = *(const float4*)(vt + 2 * e);   // block-uniform broadcast
    int s = sb + e;
    float2 xv = *(const float2*)(pl + s + ((s >> J) << 1));
    ar += v.x * xv.x + v.z * xv.y;
    ai += v.y * xv.x + v.w * xv.y;
  }
  if (SPLIT > 1) {
    red[tid] = ar; red[256 + tid] = ai;
    __syncthreads();
    if (seg == 0) {
      #pragma unroll
      for (int ss = 1; ss < SPLIT; ++ss) {
        ar += red[tid + ss * TASKS];
        ai += red[256 + tid + ss * TASKS];
      }
    }
  }
  if (seg == 0 && o0 + o < Ncu) {
    int nidx = o0 + o;
    float ndf = (float)((nidx - J2) * d);
    float rev = ndf * exp2f(-(float)(16 * (J + 1) + q) * 0.0625f);
    rev -= floorf(rev);
    float sn, cs; __sincosf(rev * 6.28318530718f, &sn, &cs);
    float* ap = ws + P.ab[J - 3] + (q * 2) * Ncu * 2;
    *(float2*)(ap + 2 * (b * Ncu + nidx)) = make_float2(ar * cs - ai * sn, ar * sn + ai * cs);
  }
}

// direct exact conv for j<=2: thread -> 4 consecutive outputs; sliding 8-float
// register window; x via ds_read_b128; coalesced float4 store.
__device__ __forceinline__ void direct_path(const float* __restrict__ x,
                                            const float* __restrict__ fr,
                                            const float* __restrict__ fi,
                                            float* __restrict__ out, int Lmax,
                                            int rem, int tid,
                                            float* xs, float* red) {
  int b = rem / 1536;
  int r2 = rem - b * 1536;
  int k = r2 >> 5;
  int t0 = (r2 & 31) << 10;
  int j = k >> 4, q = k & 15;
  int M = (int)ceil(6.0 * exp2((double)j + (double)q * 0.0625)) + 2; // >= true M
  int P = Lmax >> 1;
  float* frs = red;            // 116 floats
  float* fis = red + 128;      // 116 floats
  int xlen = 1024 + 2 * M;
  const float* xb = x + b * T_LEN;
  for (int i = tid; i < xlen; i += 256) {
    int u = t0 - M + i;
    xs[i] = (u >= 0 && u < T_LEN) ? xb[u] : 0.f;
  }
  if (tid < 4) xs[xlen + tid] = 0.f;          // zero pad (overrun reads)
  const float* frk = fr + (size_t)k * Lmax + (P - M);
  const float* fik = fi + (size_t)k * Lmax + (P - M);
  int tl = 2 * M + 1;
  for (int i = tid; i < tl; i += 256) { frs[i] = frk[i]; fis[i] = fik[i]; }
  if (tid < 3) { frs[tl + tid] = 0.f; fis[tl + tid] = 0.f; }   // zero pad
  __syncthreads();
  float ar0 = 0.f, ar1 = 0.f, ar2 = 0.f, ar3 = 0.f;
  float ai0 = 0.f, ai1 = 0.f, ai2 = 0.f, ai3 = 0.f;
  const float4* xsv = (const float4*)(xs + 4 * tid);
  float4 w0 = xsv[0];
  int groups = (tl + 3) >> 2;
  for (int g = 0; g < groups; ++g) {
    float4 w1 = xsv[g + 1];
    float4 f4 = *(const float4*)(frs + 4 * g);
    float4 h4 = *(const float4*)(fis + 4 * g);
    ar0 += f4.x * w0.x + f4.y * w0.y + f4.z * w0.z + f4.w * w0.w;
    ai0 += h4.x * w0.x + h4.y * w0.y + h4.z * w0.z + h4.w * w0.w;
    ar1 += f4.x * w0.y + f4.y * w0.z + f4.z * w0.w + f4.w * w1.x;
    ai1 += h4.x * w0.y + h4.y * w0.z + h4.z * w0.w + h4.w * w1.x;
    ar2 += f4.x * w0.z + f4.y * w0.w + f4.z * w1.x + f4.w * w1.y;
    ai2 += h4.x * w0.z + h4.y * w0.w + h4.z * w1.x + h4.w * w1.y;
    ar3 += f4.x * w0.w + f4.y * w1.x + f4.z * w1.y + f4.w * w1.z;
    ai3 += h4.x * w0.w + h4.y * w1.x + h4.z * w1.y + h4.w * w1.z;
    w0 = w1;
  }
  size_t ob = (size_t)(b * NK + k) * T_LEN + t0 + 4 * tid;
  float4 res;
  res.x = sqrtf(ar0 * ar0 + ai0 * ai0);
  res.y = sqrtf(ar1 * ar1 + ai1 * ai1);
  res.z = sqrtf(ar2 * ar2 + ai2 * ai2);
  res.w = sqrtf(ar3 * ar3 + ai3 * ai3);
  *(float4*)(out + ob) = res;
}

__global__ __launch_bounds__(256) void k_s1(const float* __restrict__ x,
                                            const float* __restrict__ fr,
                                            const float* __restrict__ fi,
                                            float* __restrict__ out, int Lmax,
                                            float* __restrict__ ws, SParams P) {
  __shared__ __align__(16) float xs[6920];    // 27.7 KB; +red -> 5 blocks/CU
  __shared__ __align__(16) float red[512];
  int bx = blockIdx.x, tid = threadIdx.x;
  int o = 0;
  #pragma unroll
  for (int t = 1; t < 10; ++t) if (bx >= P.jb[t]) o = t;
  int rem = bx - P.jb[o];
  if (o == 9) { direct_path(x, fr, fi, out, Lmax, rem, tid, xs, red); return; }
  int j = 11 - o;
  int rc = rem >> 4, q = rem & 15;
  switch (j) {
    case 11: reg_path<11, 2, 8>(x, ws, P, q, rc, tid, red); break;
    case 10: reg_path<10, 3, 4>(x, ws, P, q, rc, tid, red); break;
    case 9:  deep_path<9, 4, 4, 2, 1536>(x, ws, P, q, rc, tid, xs, red); break;
    case 8:  deep_path<8, 8, 4, 1, 1536>(x, ws, P, q, rc, tid, xs, red); break;
    case 7:  deep_path<7, 16, 2, 1, 1536>(x, ws, P, q, rc, tid, xs, red); break;
    case 6:  small_path<6, 16, 4>(x, ws, P, q, rc, tid, xs, red); break;
    case 5:  small_path<5, 32, 5>(x, ws, P, q, rc, tid, xs, red); break;
    case 4:  small_path<4, 64, 6>(x, ws, P, q, rc, tid, xs, red); break;
    default: small_path<3, 128, 7>(x, ws, P, q, rc, tid, xs, red); break;
  }
}

// ---------------- stage 2: 2 k's per block, LDS-staged A ----------------
__global__ __launch_bounds__(256) void k_stage2(const float* __restrict__ ws,
                                                float* __restrict__ out, SParams P) {
  __shared__ __align__(16) float sA[2][8][48][2];   // 6 KB
  int by = blockIdx.y;                 // 0..71 -> k pair (KDIR+2by, +1), same j
  int bx = blockIdx.x, tid = threadIdx.x;
  int k0 = KDIR + 2 * by;
  int j = k0 >> 4;
  int d = 1 << j;
  int Ncu = (32767 >> j) + 17;
  int nbb = (bx << 8) >> j;                  // base n-index for segment 0
  int sstep = 8192 >> j;
  #pragma unroll
  for (int kk = 0; kk < 2; ++kk) {
    int q = (k0 + kk) & 15;
    int ntap = 2 * j2_of_q(q) + 1;
    const float* A0 = ws + P.ab[j - 3] + (q * 2) * Ncu * 2;
    int Ci = (255 >> j) + ntap + 1;          // staged run length per segment
    #pragma unroll
    for (int pi = 0; pi < 8; ++pi) {
      int i = pi & 3, p = pi >> 2;
      const float* Ap = A0 + p * Ncu * 2 + 2 * (nbb + i * sstep);
      for (int c = tid; c < Ci; c += 256)
        *(float2*)(&sA[kk][pi][c][0]) = *(const float2*)(Ap + 2 * c);
    }
  }
  __syncthreads();
  int t0 = (bx << 8) + tid;                  // [0, 8192); outputs t0 + 8192*i
  int phi = t0 & (d - 1);
  int nl = (t0 >> j) - nbb;                  // local n offset within staged run
  float fd = (float)d;
  #pragma unroll
  for (int kk = 0; kk < 2; ++kk) {
    int k = k0 + kk, q = k & 15;
    int J2 = j2_of_q(q);
    int ntap = 2 * J2 + 1;
    float sig = 2.f * exp2f((float)(16 * j + q) * 0.0625f);
    float s2 = sig * 0.5f;
    float inv2 = 1.f / (s2 * s2);
    float u0 = (float)(phi + J2 * d);
    float eg = __expf(-0.5f * u0 * u0 * inv2);
    float mf = __expf((fd * u0 - 0.5f * fd * fd) * inv2);
    float qf = __expf(-fd * fd * inv2);
    float Z = 0.f;
    float sr0 = 0.f, si0 = 0.f, sr1 = 0.f, si1 = 0.f;
    float sr2 = 0.f, si2 = 0.f, sr3 = 0.f, si3 = 0.f;
    float tr0 = 0.f, ti0 = 0.f, tr1 = 0.f, ti1 = 0.f;
    float tr2 = 0.f, ti2 = 0.f, tr3 = 0.f, ti3 = 0.f;
    const float* base = &sA[kk][0][nl][0];
    for (int rr = 0; rr < ntap; ++rr) {
      float w = eg; eg *= mf; mf *= qf; Z += w;
      float2 a0 = *(const float2*)(base + (0 * 48 + rr) * 2);
      float2 a1 = *(const float2*)(base + (1 * 48 + rr) * 2);
      float2 a2 = *(const float2*)(base + (2 * 48 + rr) * 2);
      float2 a3 = *(const float2*)(base + (3 * 48 + rr) * 2);
      float2 b0 = *(const float2*)(base + (4 * 48 + rr) * 2);
      float2 b1 = *(const float2*)(base + (5 * 48 + rr) * 2);
      float2 b2 = *(const float2*)(base + (6 * 48 + rr) * 2);
      float2 b3 = *(const float2*)(base + (7 * 48 + rr) * 2);
      sr0 += w * a0.x; si0 += w * a0.y; sr1 += w * a1.x; si1 += w * a1.y;
      sr2 += w * a2.x; si2 += w * a2.y; sr3 += w * a3.x; si3 += w * a3.y;
      tr0 += w * b0.x; ti0 += w * b0.y; tr1 += w * b1.x; ti1 += w * b1.y;
      tr2 += w * b2.x; ti2 += w * b2.y; tr3 += w * b3.x; ti3 += w * b3.y;
    }
    float zi = 1.f / Z;
    size_t ob0 = (size_t)k * T_LEN + t0;
    size_t ob1 = (size_t)(NK + k) * T_LEN + t0;
    out[ob0]         = sqrtf(sr0 * sr0 + si0 * si0) * zi;
    out[ob0 + 8192]  = sqrtf(sr1 * sr1 + si1 * si1) * zi;
    out[ob0 + 16384] = sqrtf(sr2 * sr2 + si2 * si2) * zi;
    out[ob0 + 24576] = sqrtf(sr3 * sr3 + si3 * si3) * zi;
    out[ob1]         = sqrtf(tr0 * tr0 + ti0 * ti0) * zi;
    out[ob1 + 8192]  = sqrtf(tr1 * tr1 + ti1 * ti1) * zi;
    out[ob1 + 16384] = sqrtf(tr2 * tr2 + ti2 * ti2) * zi;
    out[ob1 + 24576] = sqrtf(tr3 * tr3 + ti3 * ti3) * zi;
  }
}

// ---------------- launch ----------------
extern "C" void kernel_launch(void* const* d_in, const int* in_sizes, int n_in,
                              void* d_out, int out_size, void* d_ws, size_t ws_size,
                              hipStream_t stream) {
  const float* x  = (const float*)d_in[0];
  const float* fr = (const float*)d_in[1];
  const float* fi = (const float*)d_in[2];
  float* out = (float*)d_out;
  float* ws  = (float*)d_ws;
  int Lmax = in_sizes[1] / NK;   // 47069

  // host-side geometry (pure CPU math, deterministic, graph-capture-safe)
  SParams Pm;
  int cur = 0, maxslot = 0;
  for (int ki = 0; ki < 144; ++ki) {
    int j = (ki + 48) >> 4, q = ki & 15;
    double sig = 2.0 * exp2(((double)(16 * j + q)) / 16.0);
    double s1 = sig * 0.86602540378443864676;
    int M1 = (int)ceil(3.5 * s1);
    int M1e = (M1 + 1) & ~1;
    int slotc = (2 * M1e + 2 + 511) & ~511;   // 512-granular
    Pm.m1e[ki] = M1e;
    Pm.slot[ki] = slotc;
    Pm.voff[ki] = cur;
    cur += 2 * slotc;
    if (slotc > maxslot) maxslot = slotc;
  }
  for (int j = 3; j <= 11; ++j) {
    Pm.ab[j - 3] = cur;
    cur += 32 * ((32767 >> j) + 17) * 2;   // 16q * 2b * Ncu * 2 words
  }
  // block ranges: j = 11 down to 3, then direct
  const int DG[5]  = {2, 3, 4, 8, 16};   // outputs per tile, j=11..7
  const int DCH[5] = {8, 4, 2, 1, 1};    // tap-chunks per tile
  const int STO[4] = {16, 32, 64, 128};  // TOUT, j=6..3
  Pm.jb[0] = 0;
  for (int o = 0; o < 9; ++o) {
    int j = 11 - o;
    int Ncu = (32767 >> j) + 17;
    int cnt;
    if (o < 5) {
      int tiles = (Ncu + DG[o] - 1) / DG[o];
      cnt = tiles * DCH[o] * 16;
    } else {
      int TOUT = STO[o - 5];
      cnt = ((Ncu + TOUT - 1) / TOUT) * 16;
    }
    Pm.jb[o + 1] = Pm.jb[o] + cnt;
  }
  Pm.jb[10] = Pm.jb[9] + (T_LEN / 1024) * KDIR * NB;   // + direct blocks (3072)

  // zero the atomic arenas (j=9,10,11)
  int zbase = Pm.ab[6];
  int zn = (Pm.ab[8] + 32 * ((32767 >> 11) + 17) * 2) - zbase;   // 10240 words

  k_pre<<<dim3((maxslot + 1023) / 1024, 145), dim3(256), 0, stream>>>(ws, Pm, zbase, zn);
  k_s1<<<dim3(Pm.jb[10]), dim3(256), 0, stream>>>(x, fr, fi, out, Lmax, ws, Pm);
  k_stage2<<<dim3(T_LEN / (256 * 4), (NK - KDIR) / 2), dim3(256), 0, stream>>>(ws, out, Pm);
}